// Round 1
// baseline (4024.613 us; speedup 1.0000x reference)
//
#include <hip/hip_runtime.h>
#include <hip/hip_bf16.h>

// Problem constants (from reference): N=100000 nodes, F_in=20, 4 heads x 16 ch = 64,
// E=3.2M edges (+N self loops), 256 graphs. All fp32 in/out.
#define FIN 20
#define HEADS 4
#define F 64
#define NEG_SLOPE 0.2f

// ---------------------------------------------------------------------------
// Kernel 1: per-node projection xh = x @ w_gat  [N,64], plus attention scalars
// a_s[n,h] = <xh[n,h,:], att_src[h,:]>, a_d likewise.
// ---------------------------------------------------------------------------
__global__ void node_prep(const float* __restrict__ x,
                          const float* __restrict__ w_gat,
                          const float* __restrict__ att_src,
                          const float* __restrict__ att_dst,
                          float* __restrict__ xh,
                          float* __restrict__ a_s,
                          float* __restrict__ a_d,
                          int n_nodes)
{
    __shared__ float w[FIN * F];     // 5 KB, [k][j]
    __shared__ float asrc[F];
    __shared__ float adst[F];
    for (int i = threadIdx.x; i < FIN * F; i += blockDim.x) w[i] = w_gat[i];
    if (threadIdx.x < F) {
        asrc[threadIdx.x] = att_src[threadIdx.x];
        adst[threadIdx.x] = att_dst[threadIdx.x];
    }
    __syncthreads();

    int n = blockIdx.x * blockDim.x + threadIdx.x;
    if (n >= n_nodes) return;

    float xv[FIN];
#pragma unroll
    for (int k = 0; k < FIN; ++k) xv[k] = x[(size_t)n * FIN + k];

    float as[HEADS] = {0.f, 0.f, 0.f, 0.f};
    float ad[HEADS] = {0.f, 0.f, 0.f, 0.f};

#pragma unroll
    for (int j4 = 0; j4 < F / 4; ++j4) {
        float4 acc = make_float4(0.f, 0.f, 0.f, 0.f);
#pragma unroll
        for (int k = 0; k < FIN; ++k) {
            float4 w4 = *(const float4*)&w[k * F + j4 * 4];
            acc.x += xv[k] * w4.x;
            acc.y += xv[k] * w4.y;
            acc.z += xv[k] * w4.z;
            acc.w += xv[k] * w4.w;
        }
        *(float4*)&xh[(size_t)n * F + j4 * 4] = acc;
        int h = j4 >> 2;           // 4 float4s per head
        int jb = j4 * 4;
        as[h] += acc.x * asrc[jb] + acc.y * asrc[jb + 1] + acc.z * asrc[jb + 2] + acc.w * asrc[jb + 3];
        ad[h] += acc.x * adst[jb] + acc.y * adst[jb + 1] + acc.z * adst[jb + 2] + acc.w * adst[jb + 3];
    }
#pragma unroll
    for (int h = 0; h < HEADS; ++h) {
        a_s[(size_t)n * HEADS + h] = as[h];
        a_d[(size_t)n * HEADS + h] = ad[h];
    }
}

// ---------------------------------------------------------------------------
// Kernel 2: softmax denominator. alpha = exp(l)/sum exp(l) is invariant to the
// reference's max-subtraction, and logits are O(1) here, so no segment-max pass.
// Edges [0,E) are real edges; [E, E+N) are the self loops (src=dst=e-E).
// ---------------------------------------------------------------------------
__global__ void edge_z(const int* __restrict__ ei, int E, int n_nodes,
                       const float* __restrict__ a_s,
                       const float* __restrict__ a_d,
                       float* __restrict__ z)
{
    int e = blockIdx.x * blockDim.x + threadIdx.x;
    int total = E + n_nodes;
    if (e >= total) return;
    int src, dst;
    if (e < E) { src = ei[e]; dst = ei[E + e]; }
    else       { src = dst = e - E; }

    float4 s = *(const float4*)&a_s[(size_t)src * 4];
    float4 d = *(const float4*)&a_d[(size_t)dst * 4];
    float l0 = s.x + d.x, l1 = s.y + d.y, l2 = s.z + d.z, l3 = s.w + d.w;
    l0 = l0 > 0.f ? l0 : NEG_SLOPE * l0;
    l1 = l1 > 0.f ? l1 : NEG_SLOPE * l1;
    l2 = l2 > 0.f ? l2 : NEG_SLOPE * l2;
    l3 = l3 > 0.f ? l3 : NEG_SLOPE * l3;
    float* zp = z + (size_t)dst * 4;
    atomicAdd(zp + 0, __expf(l0));
    atomicAdd(zp + 1, __expf(l1));
    atomicAdd(zp + 2, __expf(l2));
    atomicAdd(zp + 3, __expf(l3));
}

// ---------------------------------------------------------------------------
// Kernel 3: weighted scatter-aggregate. 16 threads per edge; thread `part`
// handles channels [part*4, part*4+4) (head = part/4). alpha recomputed from
// L2-resident a_s/a_d/z (cheaper than storing [E,4] exp values).
// ---------------------------------------------------------------------------
__global__ void edge_agg(const int* __restrict__ ei, int E, int n_nodes,
                         const float* __restrict__ a_s,
                         const float* __restrict__ a_d,
                         const float* __restrict__ z,
                         const float* __restrict__ xh,
                         float* __restrict__ out)
{
    long long tid = (long long)blockIdx.x * blockDim.x + threadIdx.x;
    long long e = tid >> 4;
    int part = (int)(tid & 15);
    long long total = (long long)E + n_nodes;
    if (e >= total) return;
    int src, dst;
    if (e < E) { src = ei[e]; dst = ei[E + e]; }
    else       { src = dst = (int)(e - E); }

    int h = part >> 2;
    float l = a_s[(size_t)src * 4 + h] + a_d[(size_t)dst * 4 + h];
    l = l > 0.f ? l : NEG_SLOPE * l;
    float alpha = __expf(l) / z[(size_t)dst * 4 + h];

    float4 v = *(const float4*)&xh[(size_t)src * F + part * 4];
    float* o = out + (size_t)dst * F + part * 4;
    atomicAdd(o + 0, alpha * v.x);
    atomicAdd(o + 1, alpha * v.y);
    atomicAdd(o + 2, alpha * v.z);
    atomicAdd(o + 3, alpha * v.w);
}

// ---------------------------------------------------------------------------
// Kernel 4: per-node MLP (64->64->32->16->16, all relu) + global mean-pool
// accumulation (sums per graph + counts). All weights live in LDS (~27.5 KB).
// ---------------------------------------------------------------------------
__global__ void __launch_bounds__(256)
mlp_pool(const float* __restrict__ gat, const float* __restrict__ b_gat,
         const float* __restrict__ w_fuse, const float* __restrict__ b_fuse,
         const float* __restrict__ w_h1, const float* __restrict__ b_h1,
         const float* __restrict__ w_h2, const float* __restrict__ b_h2,
         const float* __restrict__ w_h3, const float* __restrict__ b_h3,
         const int* __restrict__ batch,
         float* __restrict__ sums, float* __restrict__ cnts,
         int n_nodes)
{
    __shared__ float wf[64 * 64];
    __shared__ float w1[64 * 32];
    __shared__ float w2[32 * 16];
    __shared__ float w3[16 * 16];
    __shared__ float bg[64], bf[64], b1[32], b2[16], b3[16];

    for (int i = threadIdx.x; i < 64 * 64; i += blockDim.x) wf[i] = w_fuse[i];
    for (int i = threadIdx.x; i < 64 * 32; i += blockDim.x) w1[i] = w_h1[i];
    for (int i = threadIdx.x; i < 32 * 16; i += blockDim.x) w2[i] = w_h2[i];
    for (int i = threadIdx.x; i < 16 * 16; i += blockDim.x) w3[i] = w_h3[i];
    if (threadIdx.x < 64) { bg[threadIdx.x] = b_gat[threadIdx.x]; bf[threadIdx.x] = b_fuse[threadIdx.x]; }
    else if (threadIdx.x < 96)  b1[threadIdx.x - 64] = b_h1[threadIdx.x - 64];
    else if (threadIdx.x < 112) b2[threadIdx.x - 96] = b_h2[threadIdx.x - 96];
    else if (threadIdx.x < 128) b3[threadIdx.x - 112] = b_h3[threadIdx.x - 112];
    __syncthreads();

    int n = blockIdx.x * blockDim.x + threadIdx.x;
    if (n >= n_nodes) return;

    float h0[64];
#pragma unroll
    for (int j4 = 0; j4 < 16; ++j4) {
        float4 g4 = *(const float4*)&gat[(size_t)n * 64 + j4 * 4];
        h0[j4 * 4 + 0] = g4.x + bg[j4 * 4 + 0];
        h0[j4 * 4 + 1] = g4.y + bg[j4 * 4 + 1];
        h0[j4 * 4 + 2] = g4.z + bg[j4 * 4 + 2];
        h0[j4 * 4 + 3] = g4.w + bg[j4 * 4 + 3];
    }

    // layer 1: 64 -> 64, relu
    float t[64];
#pragma unroll
    for (int j4 = 0; j4 < 16; ++j4) {
        float4 acc = *(const float4*)&bf[j4 * 4];
#pragma unroll
        for (int k = 0; k < 64; ++k) {
            float4 w4 = *(const float4*)&wf[k * 64 + j4 * 4];
            acc.x += h0[k] * w4.x; acc.y += h0[k] * w4.y;
            acc.z += h0[k] * w4.z; acc.w += h0[k] * w4.w;
        }
        t[j4 * 4 + 0] = acc.x > 0.f ? acc.x : 0.f;
        t[j4 * 4 + 1] = acc.y > 0.f ? acc.y : 0.f;
        t[j4 * 4 + 2] = acc.z > 0.f ? acc.z : 0.f;
        t[j4 * 4 + 3] = acc.w > 0.f ? acc.w : 0.f;
    }
    // layer 2: 64 -> 32, relu
    float u[32];
#pragma unroll
    for (int j4 = 0; j4 < 8; ++j4) {
        float4 acc = *(const float4*)&b1[j4 * 4];
#pragma unroll
        for (int k = 0; k < 64; ++k) {
            float4 w4 = *(const float4*)&w1[k * 32 + j4 * 4];
            acc.x += t[k] * w4.x; acc.y += t[k] * w4.y;
            acc.z += t[k] * w4.z; acc.w += t[k] * w4.w;
        }
        u[j4 * 4 + 0] = acc.x > 0.f ? acc.x : 0.f;
        u[j4 * 4 + 1] = acc.y > 0.f ? acc.y : 0.f;
        u[j4 * 4 + 2] = acc.z > 0.f ? acc.z : 0.f;
        u[j4 * 4 + 3] = acc.w > 0.f ? acc.w : 0.f;
    }
    // layer 3: 32 -> 16, relu
    float v[16];
#pragma unroll
    for (int j4 = 0; j4 < 4; ++j4) {
        float4 acc = *(const float4*)&b2[j4 * 4];
#pragma unroll
        for (int k = 0; k < 32; ++k) {
            float4 w4 = *(const float4*)&w2[k * 16 + j4 * 4];
            acc.x += u[k] * w4.x; acc.y += u[k] * w4.y;
            acc.z += u[k] * w4.z; acc.w += u[k] * w4.w;
        }
        v[j4 * 4 + 0] = acc.x > 0.f ? acc.x : 0.f;
        v[j4 * 4 + 1] = acc.y > 0.f ? acc.y : 0.f;
        v[j4 * 4 + 2] = acc.z > 0.f ? acc.z : 0.f;
        v[j4 * 4 + 3] = acc.w > 0.f ? acc.w : 0.f;
    }
    // layer 4: 16 -> 16, relu
    float r[16];
#pragma unroll
    for (int j4 = 0; j4 < 4; ++j4) {
        float4 acc = *(const float4*)&b3[j4 * 4];
#pragma unroll
        for (int k = 0; k < 16; ++k) {
            float4 w4 = *(const float4*)&w3[k * 16 + j4 * 4];
            acc.x += v[k] * w4.x; acc.y += v[k] * w4.y;
            acc.z += v[k] * w4.z; acc.w += v[k] * w4.w;
        }
        r[j4 * 4 + 0] = acc.x > 0.f ? acc.x : 0.f;
        r[j4 * 4 + 1] = acc.y > 0.f ? acc.y : 0.f;
        r[j4 * 4 + 2] = acc.z > 0.f ? acc.z : 0.f;
        r[j4 * 4 + 3] = acc.w > 0.f ? acc.w : 0.f;
    }

    int b = batch[n];
    float* sp = sums + (size_t)b * 16;
#pragma unroll
    for (int j = 0; j < 16; ++j) atomicAdd(sp + j, r[j]);
    atomicAdd(cnts + b, 1.0f);
}

// ---------------------------------------------------------------------------
// Kernel 5: g = sums / max(cnt,1); two 16->3 heads. out_event then out_env.
// ---------------------------------------------------------------------------
__global__ void head_kernel(const float* __restrict__ sums,
                            const float* __restrict__ cnts,
                            const float* __restrict__ w_ev, const float* __restrict__ b_ev,
                            const float* __restrict__ w_env, const float* __restrict__ b_env,
                            float* __restrict__ out, int n_graphs)
{
    int g = blockIdx.x * blockDim.x + threadIdx.x;
    if (g >= n_graphs) return;
    float c = cnts[g];
    c = c > 1.f ? c : 1.f;
    float gg[16];
#pragma unroll
    for (int j = 0; j < 16; ++j) gg[j] = sums[(size_t)g * 16 + j] / c;
#pragma unroll
    for (int j = 0; j < 3; ++j) {
        float a = b_ev[j];
#pragma unroll
        for (int k = 0; k < 16; ++k) a += gg[k] * w_ev[k * 3 + j];
        out[(size_t)g * 3 + j] = a;
    }
#pragma unroll
    for (int j = 0; j < 3; ++j) {
        float a = b_env[j];
#pragma unroll
        for (int k = 0; k < 16; ++k) a += gg[k] * w_env[k * 3 + j];
        out[(size_t)n_graphs * 3 + (size_t)g * 3 + j] = a;
    }
}

// ---------------------------------------------------------------------------
extern "C" void kernel_launch(void* const* d_in, const int* in_sizes, int n_in,
                              void* d_out, int out_size, void* d_ws, size_t ws_size,
                              hipStream_t stream)
{
    const float* x       = (const float*)d_in[0];
    const int*   ei      = (const int*)d_in[1];
    const int*   batch   = (const int*)d_in[2];
    // d_in[3] = num_graphs scalar; fixed at 256 by the problem definition.
    const float* w_gat   = (const float*)d_in[4];
    const float* att_src = (const float*)d_in[5];
    const float* att_dst = (const float*)d_in[6];
    const float* b_gat   = (const float*)d_in[7];
    const float* w_fuse  = (const float*)d_in[8];
    const float* b_fuse  = (const float*)d_in[9];
    const float* w_h1    = (const float*)d_in[10];
    const float* b_h1    = (const float*)d_in[11];
    const float* w_h2    = (const float*)d_in[12];
    const float* b_h2    = (const float*)d_in[13];
    const float* w_h3    = (const float*)d_in[14];
    const float* b_h3    = (const float*)d_in[15];
    const float* w_ev    = (const float*)d_in[16];
    const float* b_ev    = (const float*)d_in[17];
    const float* w_env   = (const float*)d_in[18];
    const float* b_env   = (const float*)d_in[19];

    const int n_nodes  = in_sizes[0] / FIN;       // 100000
    const int E        = in_sizes[1] / 2;         // 3200000
    const int n_graphs = 256;

    // Workspace layout (floats). Total ~56.2 MB.
    float* ws   = (float*)d_ws;
    float* xh   = ws;                                    // n*64
    float* a_s  = xh  + (size_t)n_nodes * F;             // n*4
    float* a_d  = a_s + (size_t)n_nodes * HEADS;         // n*4
    float* z    = a_d + (size_t)n_nodes * HEADS;         // n*4
    float* gat  = z   + (size_t)n_nodes * HEADS;         // n*64
    float* sums = gat + (size_t)n_nodes * F;             // 256*16
    float* cnts = sums + (size_t)n_graphs * 16;          // 256

    // zero the accumulators (d_ws is poisoned 0xAA before every launch)
    hipMemsetAsync(z, 0, (size_t)n_nodes * HEADS * sizeof(float), stream);
    hipMemsetAsync(gat, 0, (size_t)n_nodes * F * sizeof(float), stream);
    hipMemsetAsync(sums, 0, (size_t)(n_graphs * 16 + n_graphs) * sizeof(float), stream);

    node_prep<<<(n_nodes + 255) / 256, 256, 0, stream>>>(
        x, w_gat, att_src, att_dst, xh, a_s, a_d, n_nodes);

    int total = E + n_nodes;
    edge_z<<<(total + 255) / 256, 256, 0, stream>>>(ei, E, n_nodes, a_s, a_d, z);

    long long t2 = (long long)total * 16;
    edge_agg<<<(int)((t2 + 255) / 256), 256, 0, stream>>>(
        ei, E, n_nodes, a_s, a_d, z, xh, gat);

    mlp_pool<<<(n_nodes + 255) / 256, 256, 0, stream>>>(
        gat, b_gat, w_fuse, b_fuse, w_h1, b_h1, w_h2, b_h2, w_h3, b_h3,
        batch, sums, cnts, n_nodes);

    head_kernel<<<(n_graphs + 255) / 256, 256, 0, stream>>>(
        sums, cnts, w_ev, b_ev, w_env, b_env, (float*)d_out, n_graphs);
}

// Round 2
// 1336.029 us; speedup vs baseline: 3.0124x; 3.0124x over previous
//
#include <hip/hip_runtime.h>
#include <hip/hip_bf16.h>

// N=100000 nodes, F_in=20, 4 heads x 16 ch = 64, E=3.2M edges (+N self loops),
// 256 graphs. All fp32.
//
// R1 design: the R0 scatter-atomic edge_agg wrote 3.3 GB of atomic RMW traffic
// (211M atomicAdds x 16B, WRITE_SIZE counter) at 2.5% VALUBusy. Replace with
// device-built dst-CSR + gather-side aggregation: zero float atomics on the
// [N,64] output, normalization (z) folded into the gather epilogue.
#define FIN 20
#define HEADS 4
#define F 64
#define NEG_SLOPE 0.2f
#define SCAN_THREADS 1024

// ---------------------------------------------------------------------------
// Kernel 1: per-node projection xh = x @ w_gat [N,64] + attention scalars.
// ---------------------------------------------------------------------------
__global__ void node_prep(const float* __restrict__ x,
                          const float* __restrict__ w_gat,
                          const float* __restrict__ att_src,
                          const float* __restrict__ att_dst,
                          float* __restrict__ xh,
                          float* __restrict__ a_s,
                          float* __restrict__ a_d,
                          int n_nodes)
{
    __shared__ float w[FIN * F];
    __shared__ float asrc[F];
    __shared__ float adst[F];
    for (int i = threadIdx.x; i < FIN * F; i += blockDim.x) w[i] = w_gat[i];
    if (threadIdx.x < F) {
        asrc[threadIdx.x] = att_src[threadIdx.x];
        adst[threadIdx.x] = att_dst[threadIdx.x];
    }
    __syncthreads();

    int n = blockIdx.x * blockDim.x + threadIdx.x;
    if (n >= n_nodes) return;

    float xv[FIN];
#pragma unroll
    for (int k = 0; k < FIN; ++k) xv[k] = x[(size_t)n * FIN + k];

    float as[HEADS] = {0.f, 0.f, 0.f, 0.f};
    float ad[HEADS] = {0.f, 0.f, 0.f, 0.f};

#pragma unroll
    for (int j4 = 0; j4 < F / 4; ++j4) {
        float4 acc = make_float4(0.f, 0.f, 0.f, 0.f);
#pragma unroll
        for (int k = 0; k < FIN; ++k) {
            float4 w4 = *(const float4*)&w[k * F + j4 * 4];
            acc.x += xv[k] * w4.x;
            acc.y += xv[k] * w4.y;
            acc.z += xv[k] * w4.z;
            acc.w += xv[k] * w4.w;
        }
        *(float4*)&xh[(size_t)n * F + j4 * 4] = acc;
        int h = j4 >> 2;
        int jb = j4 * 4;
        as[h] += acc.x * asrc[jb] + acc.y * asrc[jb + 1] + acc.z * asrc[jb + 2] + acc.w * asrc[jb + 3];
        ad[h] += acc.x * adst[jb] + acc.y * adst[jb + 1] + acc.z * adst[jb + 2] + acc.w * adst[jb + 3];
    }
#pragma unroll
    for (int h = 0; h < HEADS; ++h) {
        a_s[(size_t)n * HEADS + h] = as[h];
        a_d[(size_t)n * HEADS + h] = ad[h];
    }
}

// ---------------------------------------------------------------------------
// CSR build step 1: deg[n] = 1 (self loop) then += real-edge histogram.
// ---------------------------------------------------------------------------
__global__ void deg_init(int* __restrict__ deg, int n_nodes)
{
    int n = blockIdx.x * blockDim.x + threadIdx.x;
    if (n < n_nodes) deg[n] = 1;
}

__global__ void deg_hist(const int* __restrict__ ei, int E, int* __restrict__ deg)
{
    int e = blockIdx.x * blockDim.x + threadIdx.x;
    if (e >= E) return;
    atomicAdd(&deg[ei[E + e]], 1);
}

// ---------------------------------------------------------------------------
// CSR build step 2: exclusive scan of deg -> off[0..n], cursor = off.
// Single block, 1024 threads, ~98 elements/thread + Hillis-Steele over LDS.
// ---------------------------------------------------------------------------
__global__ void __launch_bounds__(SCAN_THREADS)
deg_scan(const int* __restrict__ deg, int* __restrict__ off,
         int* __restrict__ cursor, int n)
{
    __shared__ int sh[SCAN_THREADS];
    int tid = threadIdx.x;
    int chunk = (n + SCAN_THREADS - 1) / SCAN_THREADS;
    int start = tid * chunk;
    int end = start + chunk; if (end > n) end = n; if (start > n) start = n;

    int s = 0;
    for (int i = start; i < end; ++i) s += deg[i];
    sh[tid] = s;
    __syncthreads();
#pragma unroll
    for (int d = 1; d < SCAN_THREADS; d <<= 1) {
        int v = (tid >= d) ? sh[tid - d] : 0;
        __syncthreads();
        sh[tid] += v;
        __syncthreads();
    }
    int run = (tid == 0) ? 0 : sh[tid - 1];
    for (int i = start; i < end; ++i) {
        off[i] = run;
        cursor[i] = run;
        run += deg[i];
    }
    if (end == n) off[n] = run;   // total = E + n_nodes
}

// ---------------------------------------------------------------------------
// CSR build step 3: scatter src ids into dst buckets. e in [E,E+N) = self loop.
// ---------------------------------------------------------------------------
__global__ void csr_scatter(const int* __restrict__ ei, int E, int n_nodes,
                            int* __restrict__ cursor, int* __restrict__ srcs)
{
    int e = blockIdx.x * blockDim.x + threadIdx.x;
    int total = E + n_nodes;
    if (e >= total) return;
    int src, dst;
    if (e < E) { src = ei[e]; dst = ei[E + e]; }
    else       { src = dst = e - E; }
    int p = atomicAdd(&cursor[dst], 1);
    srcs[p] = src;
}

// ---------------------------------------------------------------------------
// Kernel: gather-side aggregation. 16 lanes per dst node; lane `part` owns
// channels [part*4, part*4+4), head = part>>2. Accumulates unnormalized
// sum and z in registers; writes out = acc/z once. No atomics.
// ---------------------------------------------------------------------------
__global__ void gat_agg(const int* __restrict__ off,
                        const int* __restrict__ srcs,
                        const float* __restrict__ a_s,
                        const float* __restrict__ a_d,
                        const float* __restrict__ xh,
                        float* __restrict__ out,
                        int n_nodes)
{
    long long tid = (long long)blockIdx.x * blockDim.x + threadIdx.x;
    int n = (int)(tid >> 4);
    int part = (int)(tid & 15);
    if (n >= n_nodes) return;
    int h = part >> 2;

    int kb = off[n];
    int ke = off[n + 1];
    float adh = a_d[(size_t)n * 4 + h];

    float4 acc = make_float4(0.f, 0.f, 0.f, 0.f);
    float zacc = 0.f;
    for (int k = kb; k < ke; ++k) {
        int s = srcs[k];
        float l = a_s[(size_t)s * 4 + h] + adh;
        l = l > 0.f ? l : NEG_SLOPE * l;
        float e = __expf(l);
        zacc += e;
        float4 v = *(const float4*)&xh[(size_t)s * F + part * 4];
        acc.x += e * v.x; acc.y += e * v.y;
        acc.z += e * v.z; acc.w += e * v.w;
    }
    float inv = 1.f / zacc;
    acc.x *= inv; acc.y *= inv; acc.z *= inv; acc.w *= inv;
    *(float4*)&out[(size_t)n * F + part * 4] = acc;
}

// ---------------------------------------------------------------------------
// Kernel: per-node MLP (64->64->32->16->16, relu) + mean-pool accumulation.
// ---------------------------------------------------------------------------
__global__ void __launch_bounds__(256)
mlp_pool(const float* __restrict__ gat, const float* __restrict__ b_gat,
         const float* __restrict__ w_fuse, const float* __restrict__ b_fuse,
         const float* __restrict__ w_h1, const float* __restrict__ b_h1,
         const float* __restrict__ w_h2, const float* __restrict__ b_h2,
         const float* __restrict__ w_h3, const float* __restrict__ b_h3,
         const int* __restrict__ batch,
         float* __restrict__ sums, float* __restrict__ cnts,
         int n_nodes)
{
    __shared__ float wf[64 * 64];
    __shared__ float w1[64 * 32];
    __shared__ float w2[32 * 16];
    __shared__ float w3[16 * 16];
    __shared__ float bg[64], bf[64], b1[32], b2[16], b3[16];

    for (int i = threadIdx.x; i < 64 * 64; i += blockDim.x) wf[i] = w_fuse[i];
    for (int i = threadIdx.x; i < 64 * 32; i += blockDim.x) w1[i] = w_h1[i];
    for (int i = threadIdx.x; i < 32 * 16; i += blockDim.x) w2[i] = w_h2[i];
    for (int i = threadIdx.x; i < 16 * 16; i += blockDim.x) w3[i] = w_h3[i];
    if (threadIdx.x < 64) { bg[threadIdx.x] = b_gat[threadIdx.x]; bf[threadIdx.x] = b_fuse[threadIdx.x]; }
    else if (threadIdx.x < 96)  b1[threadIdx.x - 64] = b_h1[threadIdx.x - 64];
    else if (threadIdx.x < 112) b2[threadIdx.x - 96] = b_h2[threadIdx.x - 96];
    else if (threadIdx.x < 128) b3[threadIdx.x - 112] = b_h3[threadIdx.x - 112];
    __syncthreads();

    int n = blockIdx.x * blockDim.x + threadIdx.x;
    if (n >= n_nodes) return;

    float h0[64];
#pragma unroll
    for (int j4 = 0; j4 < 16; ++j4) {
        float4 g4 = *(const float4*)&gat[(size_t)n * 64 + j4 * 4];
        h0[j4 * 4 + 0] = g4.x + bg[j4 * 4 + 0];
        h0[j4 * 4 + 1] = g4.y + bg[j4 * 4 + 1];
        h0[j4 * 4 + 2] = g4.z + bg[j4 * 4 + 2];
        h0[j4 * 4 + 3] = g4.w + bg[j4 * 4 + 3];
    }

    float t[64];
#pragma unroll
    for (int j4 = 0; j4 < 16; ++j4) {
        float4 acc = *(const float4*)&bf[j4 * 4];
#pragma unroll
        for (int k = 0; k < 64; ++k) {
            float4 w4 = *(const float4*)&wf[k * 64 + j4 * 4];
            acc.x += h0[k] * w4.x; acc.y += h0[k] * w4.y;
            acc.z += h0[k] * w4.z; acc.w += h0[k] * w4.w;
        }
        t[j4 * 4 + 0] = acc.x > 0.f ? acc.x : 0.f;
        t[j4 * 4 + 1] = acc.y > 0.f ? acc.y : 0.f;
        t[j4 * 4 + 2] = acc.z > 0.f ? acc.z : 0.f;
        t[j4 * 4 + 3] = acc.w > 0.f ? acc.w : 0.f;
    }
    float u[32];
#pragma unroll
    for (int j4 = 0; j4 < 8; ++j4) {
        float4 acc = *(const float4*)&b1[j4 * 4];
#pragma unroll
        for (int k = 0; k < 64; ++k) {
            float4 w4 = *(const float4*)&w1[k * 32 + j4 * 4];
            acc.x += t[k] * w4.x; acc.y += t[k] * w4.y;
            acc.z += t[k] * w4.z; acc.w += t[k] * w4.w;
        }
        u[j4 * 4 + 0] = acc.x > 0.f ? acc.x : 0.f;
        u[j4 * 4 + 1] = acc.y > 0.f ? acc.y : 0.f;
        u[j4 * 4 + 2] = acc.z > 0.f ? acc.z : 0.f;
        u[j4 * 4 + 3] = acc.w > 0.f ? acc.w : 0.f;
    }
    float v[16];
#pragma unroll
    for (int j4 = 0; j4 < 4; ++j4) {
        float4 acc = *(const float4*)&b2[j4 * 4];
#pragma unroll
        for (int k = 0; k < 32; ++k) {
            float4 w4 = *(const float4*)&w2[k * 16 + j4 * 4];
            acc.x += u[k] * w4.x; acc.y += u[k] * w4.y;
            acc.z += u[k] * w4.z; acc.w += u[k] * w4.w;
        }
        v[j4 * 4 + 0] = acc.x > 0.f ? acc.x : 0.f;
        v[j4 * 4 + 1] = acc.y > 0.f ? acc.y : 0.f;
        v[j4 * 4 + 2] = acc.z > 0.f ? acc.z : 0.f;
        v[j4 * 4 + 3] = acc.w > 0.f ? acc.w : 0.f;
    }
    float r[16];
#pragma unroll
    for (int j4 = 0; j4 < 4; ++j4) {
        float4 acc = *(const float4*)&b3[j4 * 4];
#pragma unroll
        for (int k = 0; k < 16; ++k) {
            float4 w4 = *(const float4*)&w3[k * 16 + j4 * 4];
            acc.x += v[k] * w4.x; acc.y += v[k] * w4.y;
            acc.z += v[k] * w4.z; acc.w += v[k] * w4.w;
        }
        r[j4 * 4 + 0] = acc.x > 0.f ? acc.x : 0.f;
        r[j4 * 4 + 1] = acc.y > 0.f ? acc.y : 0.f;
        r[j4 * 4 + 2] = acc.z > 0.f ? acc.z : 0.f;
        r[j4 * 4 + 3] = acc.w > 0.f ? acc.w : 0.f;
    }

    int b = batch[n];
    float* sp = sums + (size_t)b * 16;
#pragma unroll
    for (int j = 0; j < 16; ++j) atomicAdd(sp + j, r[j]);
    atomicAdd(cnts + b, 1.0f);
}

// ---------------------------------------------------------------------------
// Kernel: g = sums / max(cnt,1); two 16->3 heads.
// ---------------------------------------------------------------------------
__global__ void head_kernel(const float* __restrict__ sums,
                            const float* __restrict__ cnts,
                            const float* __restrict__ w_ev, const float* __restrict__ b_ev,
                            const float* __restrict__ w_env, const float* __restrict__ b_env,
                            float* __restrict__ out, int n_graphs)
{
    int g = blockIdx.x * blockDim.x + threadIdx.x;
    if (g >= n_graphs) return;
    float c = cnts[g];
    c = c > 1.f ? c : 1.f;
    float gg[16];
#pragma unroll
    for (int j = 0; j < 16; ++j) gg[j] = sums[(size_t)g * 16 + j] / c;
#pragma unroll
    for (int j = 0; j < 3; ++j) {
        float a = b_ev[j];
#pragma unroll
        for (int k = 0; k < 16; ++k) a += gg[k] * w_ev[k * 3 + j];
        out[(size_t)g * 3 + j] = a;
    }
#pragma unroll
    for (int j = 0; j < 3; ++j) {
        float a = b_env[j];
#pragma unroll
        for (int k = 0; k < 16; ++k) a += gg[k] * w_env[k * 3 + j];
        out[(size_t)n_graphs * 3 + (size_t)g * 3 + j] = a;
    }
}

// ---------------------------------------------------------------------------
extern "C" void kernel_launch(void* const* d_in, const int* in_sizes, int n_in,
                              void* d_out, int out_size, void* d_ws, size_t ws_size,
                              hipStream_t stream)
{
    const float* x       = (const float*)d_in[0];
    const int*   ei      = (const int*)d_in[1];
    const int*   batch   = (const int*)d_in[2];
    const float* w_gat   = (const float*)d_in[4];
    const float* att_src = (const float*)d_in[5];
    const float* att_dst = (const float*)d_in[6];
    const float* b_gat   = (const float*)d_in[7];
    const float* w_fuse  = (const float*)d_in[8];
    const float* b_fuse  = (const float*)d_in[9];
    const float* w_h1    = (const float*)d_in[10];
    const float* b_h1    = (const float*)d_in[11];
    const float* w_h2    = (const float*)d_in[12];
    const float* b_h2    = (const float*)d_in[13];
    const float* w_h3    = (const float*)d_in[14];
    const float* b_h3    = (const float*)d_in[15];
    const float* w_ev    = (const float*)d_in[16];
    const float* b_ev    = (const float*)d_in[17];
    const float* w_env   = (const float*)d_in[18];
    const float* b_env   = (const float*)d_in[19];

    const int n_nodes  = in_sizes[0] / FIN;       // 100000
    const int E        = in_sizes[1] / 2;         // 3200000
    const int n_graphs = 256;
    const int total    = E + n_nodes;             // edges incl self loops

    // Workspace layout (floats/ints). ~68.5 MB.
    float* ws     = (float*)d_ws;
    float* xh     = ws;                                   // n*64
    float* a_s    = xh   + (size_t)n_nodes * F;           // n*4
    float* a_d    = a_s  + (size_t)n_nodes * HEADS;       // n*4
    float* gat    = a_d  + (size_t)n_nodes * HEADS;       // n*64
    float* sums   = gat  + (size_t)n_nodes * F;           // 256*16
    float* cnts   = sums + (size_t)n_graphs * 16;         // 256
    int*   deg    = (int*)(cnts + n_graphs);              // n
    int*   off    = deg    + n_nodes;                     // n+1
    int*   cursor = off    + n_nodes + 1;                 // n
    int*   srcs   = cursor + n_nodes;                     // E+n

    hipMemsetAsync(sums, 0, (size_t)(n_graphs * 16 + n_graphs) * sizeof(float), stream);

    node_prep<<<(n_nodes + 255) / 256, 256, 0, stream>>>(
        x, w_gat, att_src, att_dst, xh, a_s, a_d, n_nodes);

    // CSR build (by dst), rebuilt every call (no cross-call state).
    deg_init<<<(n_nodes + 255) / 256, 256, 0, stream>>>(deg, n_nodes);
    deg_hist<<<(E + 255) / 256, 256, 0, stream>>>(ei, E, deg);
    deg_scan<<<1, SCAN_THREADS, 0, stream>>>(deg, off, cursor, n_nodes);
    csr_scatter<<<(total + 255) / 256, 256, 0, stream>>>(ei, E, n_nodes, cursor, srcs);

    long long t2 = (long long)n_nodes * 16;
    gat_agg<<<(int)((t2 + 255) / 256), 256, 0, stream>>>(
        off, srcs, a_s, a_d, xh, gat, n_nodes);

    mlp_pool<<<(n_nodes + 255) / 256, 256, 0, stream>>>(
        gat, b_gat, w_fuse, b_fuse, w_h1, b_h1, w_h2, b_h2, w_h3, b_h3,
        batch, sums, cnts, n_nodes);

    head_kernel<<<(n_graphs + 255) / 256, 256, 0, stream>>>(
        sums, cnts, w_ev, b_ev, w_env, b_env, (float*)d_out, n_graphs);
}

// Round 3
// 1103.658 us; speedup vs baseline: 3.6466x; 1.2105x over previous
//
#include <hip/hip_runtime.h>
#include <hip/hip_bf16.h>

// N=100000 nodes, F_in=20, 4 heads x 16 ch = 64, E=3.2M edges (+N self loops),
// 256 graphs. All fp32.
//
// R2: (a) mlp_pool was spilling h0[64]+t[64] to scratch (VGPR_Count=92,
// WRITE_SIZE 53MB == 100k x 512B) -> __launch_bounds__(256,1) allows ~512
// VGPRs, no spill. (b) 3-phase coalesced scan replaces the single-block
// strided scan; self-loop +1/node folded into offsets (off[i]=scan(deg)[i]+i).
#define FIN 20
#define HEADS 4
#define F 64
#define NEG_SLOPE 0.2f
#define SCAN_BLOCK 256
#define SCAN_ITEMS 4
#define SCAN_CHUNK (SCAN_BLOCK * SCAN_ITEMS)   // 1024 elements / block

// ---------------------------------------------------------------------------
// Kernel 1: per-node projection xh = x @ w_gat [N,64] + attention scalars.
// ---------------------------------------------------------------------------
__global__ void node_prep(const float* __restrict__ x,
                          const float* __restrict__ w_gat,
                          const float* __restrict__ att_src,
                          const float* __restrict__ att_dst,
                          float* __restrict__ xh,
                          float* __restrict__ a_s,
                          float* __restrict__ a_d,
                          int n_nodes)
{
    __shared__ float w[FIN * F];
    __shared__ float asrc[F];
    __shared__ float adst[F];
    for (int i = threadIdx.x; i < FIN * F; i += blockDim.x) w[i] = w_gat[i];
    if (threadIdx.x < F) {
        asrc[threadIdx.x] = att_src[threadIdx.x];
        adst[threadIdx.x] = att_dst[threadIdx.x];
    }
    __syncthreads();

    int n = blockIdx.x * blockDim.x + threadIdx.x;
    if (n >= n_nodes) return;

    float xv[FIN];
#pragma unroll
    for (int k = 0; k < FIN; ++k) xv[k] = x[(size_t)n * FIN + k];

    float as[HEADS] = {0.f, 0.f, 0.f, 0.f};
    float ad[HEADS] = {0.f, 0.f, 0.f, 0.f};

#pragma unroll
    for (int j4 = 0; j4 < F / 4; ++j4) {
        float4 acc = make_float4(0.f, 0.f, 0.f, 0.f);
#pragma unroll
        for (int k = 0; k < FIN; ++k) {
            float4 w4 = *(const float4*)&w[k * F + j4 * 4];
            acc.x += xv[k] * w4.x;
            acc.y += xv[k] * w4.y;
            acc.z += xv[k] * w4.z;
            acc.w += xv[k] * w4.w;
        }
        *(float4*)&xh[(size_t)n * F + j4 * 4] = acc;
        int h = j4 >> 2;
        int jb = j4 * 4;
        as[h] += acc.x * asrc[jb] + acc.y * asrc[jb + 1] + acc.z * asrc[jb + 2] + acc.w * asrc[jb + 3];
        ad[h] += acc.x * adst[jb] + acc.y * adst[jb + 1] + acc.z * adst[jb + 2] + acc.w * adst[jb + 3];
    }
#pragma unroll
    for (int h = 0; h < HEADS; ++h) {
        a_s[(size_t)n * HEADS + h] = as[h];
        a_d[(size_t)n * HEADS + h] = ad[h];
    }
}

// ---------------------------------------------------------------------------
// CSR build: deg = real-edge histogram (deg memset to 0 beforehand).
// ---------------------------------------------------------------------------
__global__ void deg_hist(const int* __restrict__ ei, int E, int* __restrict__ deg)
{
    int e = blockIdx.x * blockDim.x + threadIdx.x;
    if (e >= E) return;
    atomicAdd(&deg[ei[E + e]], 1);
}

// ---------------------------------------------------------------------------
// 3-phase exclusive scan of deg. Self-loops folded in: off[i]=scan(deg)[i]+i.
// ---------------------------------------------------------------------------
__global__ void scan_p1(const int* __restrict__ deg, int* __restrict__ bsums, int n)
{
    __shared__ int sh[SCAN_BLOCK];
    int base = blockIdx.x * SCAN_CHUNK + threadIdx.x * SCAN_ITEMS;
    int s = 0;
    if (base + SCAN_ITEMS <= n) {
        int4 v = *(const int4*)&deg[base];
        s = v.x + v.y + v.z + v.w;
    } else {
        for (int j = 0; j < SCAN_ITEMS; ++j) { int i = base + j; if (i < n) s += deg[i]; }
    }
    sh[threadIdx.x] = s;
    __syncthreads();
    for (int d = SCAN_BLOCK / 2; d > 0; d >>= 1) {
        if (threadIdx.x < d) sh[threadIdx.x] += sh[threadIdx.x + d];
        __syncthreads();
    }
    if (threadIdx.x == 0) bsums[blockIdx.x] = sh[0];
}

__global__ void scan_p2(int* __restrict__ bsums, int nb)
{
    __shared__ int sh[128];
    int t = threadIdx.x;
    int v = (t < nb) ? bsums[t] : 0;
    sh[t] = v;
    __syncthreads();
    for (int d = 1; d < 128; d <<= 1) {
        int w = (t >= d) ? sh[t - d] : 0;
        __syncthreads();
        sh[t] += w;
        __syncthreads();
    }
    if (t < nb) bsums[t] = (t == 0) ? 0 : sh[t - 1];   // exclusive
}

__global__ void scan_p3(const int* __restrict__ deg, const int* __restrict__ bpre,
                        int* __restrict__ off, int* __restrict__ cursor,
                        int n, int total)
{
    __shared__ int sh[SCAN_BLOCK];
    int t = threadIdx.x;
    int base = blockIdx.x * SCAN_CHUNK + t * SCAN_ITEMS;
    int v[SCAN_ITEMS];
    int s = 0;
    if (base + SCAN_ITEMS <= n) {
        int4 q = *(const int4*)&deg[base];
        v[0] = q.x; v[1] = q.y; v[2] = q.z; v[3] = q.w;
        s = q.x + q.y + q.z + q.w;
    } else {
#pragma unroll
        for (int j = 0; j < SCAN_ITEMS; ++j) { int i = base + j; v[j] = (i < n) ? deg[i] : 0; s += v[j]; }
    }
    sh[t] = s;
    __syncthreads();
    for (int d = 1; d < SCAN_BLOCK; d <<= 1) {
        int w = (t >= d) ? sh[t - d] : 0;
        __syncthreads();
        sh[t] += w;
        __syncthreads();
    }
    int run = bpre[blockIdx.x] + ((t == 0) ? 0 : sh[t - 1]);
#pragma unroll
    for (int j = 0; j < SCAN_ITEMS; ++j) {
        int i = base + j;
        if (i < n) {
            int o = run + i;        // +i accounts for one self-loop per node
            off[i] = o;
            cursor[i] = o;
            run += v[j];
        }
    }
    if (blockIdx.x == 0 && t == 0) off[n] = total;
}

// ---------------------------------------------------------------------------
// CSR scatter: src ids into dst buckets. e in [E,E+N) = self loop.
// ---------------------------------------------------------------------------
__global__ void csr_scatter(const int* __restrict__ ei, int E, int n_nodes,
                            int* __restrict__ cursor, int* __restrict__ srcs)
{
    int e = blockIdx.x * blockDim.x + threadIdx.x;
    int total = E + n_nodes;
    if (e >= total) return;
    int src, dst;
    if (e < E) { src = ei[e]; dst = ei[E + e]; }
    else       { src = dst = e - E; }
    int p = atomicAdd(&cursor[dst], 1);
    srcs[p] = src;
}

// ---------------------------------------------------------------------------
// Gather-side aggregation. 16 lanes per dst node; lane `part` owns channels
// [part*4, part*4+4), head = part>>2. No atomics; z folded into epilogue.
// ---------------------------------------------------------------------------
__global__ void gat_agg(const int* __restrict__ off,
                        const int* __restrict__ srcs,
                        const float* __restrict__ a_s,
                        const float* __restrict__ a_d,
                        const float* __restrict__ xh,
                        float* __restrict__ out,
                        int n_nodes)
{
    long long tid = (long long)blockIdx.x * blockDim.x + threadIdx.x;
    int n = (int)(tid >> 4);
    int part = (int)(tid & 15);
    if (n >= n_nodes) return;
    int h = part >> 2;

    int kb = off[n];
    int ke = off[n + 1];
    float adh = a_d[(size_t)n * 4 + h];

    float4 acc = make_float4(0.f, 0.f, 0.f, 0.f);
    float zacc = 0.f;
    for (int k = kb; k < ke; ++k) {
        int s = srcs[k];
        float l = a_s[(size_t)s * 4 + h] + adh;
        l = l > 0.f ? l : NEG_SLOPE * l;
        float e = __expf(l);
        zacc += e;
        float4 v = *(const float4*)&xh[(size_t)s * F + part * 4];
        acc.x += e * v.x; acc.y += e * v.y;
        acc.z += e * v.z; acc.w += e * v.w;
    }
    float inv = 1.f / zacc;
    acc.x *= inv; acc.y *= inv; acc.z *= inv; acc.w *= inv;
    *(float4*)&out[(size_t)n * F + part * 4] = acc;
}

// ---------------------------------------------------------------------------
// Per-node MLP (64->64->32->16->16, relu) + mean-pool accumulation.
// __launch_bounds__(256,1): needs ~160 live VGPRs (h0[64]+t[64]); the default
// cap made R1 spill 512B/thread to scratch (53MB WRITE_SIZE).
// ---------------------------------------------------------------------------
__global__ void __launch_bounds__(256, 1)
mlp_pool(const float* __restrict__ gat, const float* __restrict__ b_gat,
         const float* __restrict__ w_fuse, const float* __restrict__ b_fuse,
         const float* __restrict__ w_h1, const float* __restrict__ b_h1,
         const float* __restrict__ w_h2, const float* __restrict__ b_h2,
         const float* __restrict__ w_h3, const float* __restrict__ b_h3,
         const int* __restrict__ batch,
         float* __restrict__ sums, float* __restrict__ cnts,
         int n_nodes)
{
    __shared__ float wf[64 * 64];
    __shared__ float w1[64 * 32];
    __shared__ float w2[32 * 16];
    __shared__ float w3[16 * 16];
    __shared__ float bg[64], bf[64], b1[32], b2[16], b3[16];

    for (int i = threadIdx.x; i < 64 * 64; i += blockDim.x) wf[i] = w_fuse[i];
    for (int i = threadIdx.x; i < 64 * 32; i += blockDim.x) w1[i] = w_h1[i];
    for (int i = threadIdx.x; i < 32 * 16; i += blockDim.x) w2[i] = w_h2[i];
    for (int i = threadIdx.x; i < 16 * 16; i += blockDim.x) w3[i] = w_h3[i];
    if (threadIdx.x < 64) { bg[threadIdx.x] = b_gat[threadIdx.x]; bf[threadIdx.x] = b_fuse[threadIdx.x]; }
    else if (threadIdx.x < 96)  b1[threadIdx.x - 64] = b_h1[threadIdx.x - 64];
    else if (threadIdx.x < 112) b2[threadIdx.x - 96] = b_h2[threadIdx.x - 96];
    else if (threadIdx.x < 128) b3[threadIdx.x - 112] = b_h3[threadIdx.x - 112];
    __syncthreads();

    int n = blockIdx.x * blockDim.x + threadIdx.x;
    if (n >= n_nodes) return;

    float h0[64];
#pragma unroll
    for (int j4 = 0; j4 < 16; ++j4) {
        float4 g4 = *(const float4*)&gat[(size_t)n * 64 + j4 * 4];
        h0[j4 * 4 + 0] = g4.x + bg[j4 * 4 + 0];
        h0[j4 * 4 + 1] = g4.y + bg[j4 * 4 + 1];
        h0[j4 * 4 + 2] = g4.z + bg[j4 * 4 + 2];
        h0[j4 * 4 + 3] = g4.w + bg[j4 * 4 + 3];
    }

    float t[64];
#pragma unroll
    for (int j4 = 0; j4 < 16; ++j4) {
        float4 acc = *(const float4*)&bf[j4 * 4];
#pragma unroll
        for (int k = 0; k < 64; ++k) {
            float4 w4 = *(const float4*)&wf[k * 64 + j4 * 4];
            acc.x += h0[k] * w4.x; acc.y += h0[k] * w4.y;
            acc.z += h0[k] * w4.z; acc.w += h0[k] * w4.w;
        }
        t[j4 * 4 + 0] = acc.x > 0.f ? acc.x : 0.f;
        t[j4 * 4 + 1] = acc.y > 0.f ? acc.y : 0.f;
        t[j4 * 4 + 2] = acc.z > 0.f ? acc.z : 0.f;
        t[j4 * 4 + 3] = acc.w > 0.f ? acc.w : 0.f;
    }
    float u[32];
#pragma unroll
    for (int j4 = 0; j4 < 8; ++j4) {
        float4 acc = *(const float4*)&b1[j4 * 4];
#pragma unroll
        for (int k = 0; k < 64; ++k) {
            float4 w4 = *(const float4*)&w1[k * 32 + j4 * 4];
            acc.x += t[k] * w4.x; acc.y += t[k] * w4.y;
            acc.z += t[k] * w4.z; acc.w += t[k] * w4.w;
        }
        u[j4 * 4 + 0] = acc.x > 0.f ? acc.x : 0.f;
        u[j4 * 4 + 1] = acc.y > 0.f ? acc.y : 0.f;
        u[j4 * 4 + 2] = acc.z > 0.f ? acc.z : 0.f;
        u[j4 * 4 + 3] = acc.w > 0.f ? acc.w : 0.f;
    }
    float v[16];
#pragma unroll
    for (int j4 = 0; j4 < 4; ++j4) {
        float4 acc = *(const float4*)&b2[j4 * 4];
#pragma unroll
        for (int k = 0; k < 32; ++k) {
            float4 w4 = *(const float4*)&w2[k * 16 + j4 * 4];
            acc.x += u[k] * w4.x; acc.y += u[k] * w4.y;
            acc.z += u[k] * w4.z; acc.w += u[k] * w4.w;
        }
        v[j4 * 4 + 0] = acc.x > 0.f ? acc.x : 0.f;
        v[j4 * 4 + 1] = acc.y > 0.f ? acc.y : 0.f;
        v[j4 * 4 + 2] = acc.z > 0.f ? acc.z : 0.f;
        v[j4 * 4 + 3] = acc.w > 0.f ? acc.w : 0.f;
    }
    float r[16];
#pragma unroll
    for (int j4 = 0; j4 < 4; ++j4) {
        float4 acc = *(const float4*)&b3[j4 * 4];
#pragma unroll
        for (int k = 0; k < 16; ++k) {
            float4 w4 = *(const float4*)&w3[k * 16 + j4 * 4];
            acc.x += v[k] * w4.x; acc.y += v[k] * w4.y;
            acc.z += v[k] * w4.z; acc.w += v[k] * w4.w;
        }
        r[j4 * 4 + 0] = acc.x > 0.f ? acc.x : 0.f;
        r[j4 * 4 + 1] = acc.y > 0.f ? acc.y : 0.f;
        r[j4 * 4 + 2] = acc.z > 0.f ? acc.z : 0.f;
        r[j4 * 4 + 3] = acc.w > 0.f ? acc.w : 0.f;
    }

    int b = batch[n];
    float* sp = sums + (size_t)b * 16;
#pragma unroll
    for (int j = 0; j < 16; ++j) atomicAdd(sp + j, r[j]);
    atomicAdd(cnts + b, 1.0f);
}

// ---------------------------------------------------------------------------
// g = sums / max(cnt,1); two 16->3 heads.
// ---------------------------------------------------------------------------
__global__ void head_kernel(const float* __restrict__ sums,
                            const float* __restrict__ cnts,
                            const float* __restrict__ w_ev, const float* __restrict__ b_ev,
                            const float* __restrict__ w_env, const float* __restrict__ b_env,
                            float* __restrict__ out, int n_graphs)
{
    int g = blockIdx.x * blockDim.x + threadIdx.x;
    if (g >= n_graphs) return;
    float c = cnts[g];
    c = c > 1.f ? c : 1.f;
    float gg[16];
#pragma unroll
    for (int j = 0; j < 16; ++j) gg[j] = sums[(size_t)g * 16 + j] / c;
#pragma unroll
    for (int j = 0; j < 3; ++j) {
        float a = b_ev[j];
#pragma unroll
        for (int k = 0; k < 16; ++k) a += gg[k] * w_ev[k * 3 + j];
        out[(size_t)g * 3 + j] = a;
    }
#pragma unroll
    for (int j = 0; j < 3; ++j) {
        float a = b_env[j];
#pragma unroll
        for (int k = 0; k < 16; ++k) a += gg[k] * w_env[k * 3 + j];
        out[(size_t)n_graphs * 3 + (size_t)g * 3 + j] = a;
    }
}

// ---------------------------------------------------------------------------
extern "C" void kernel_launch(void* const* d_in, const int* in_sizes, int n_in,
                              void* d_out, int out_size, void* d_ws, size_t ws_size,
                              hipStream_t stream)
{
    const float* x       = (const float*)d_in[0];
    const int*   ei      = (const int*)d_in[1];
    const int*   batch   = (const int*)d_in[2];
    const float* w_gat   = (const float*)d_in[4];
    const float* att_src = (const float*)d_in[5];
    const float* att_dst = (const float*)d_in[6];
    const float* b_gat   = (const float*)d_in[7];
    const float* w_fuse  = (const float*)d_in[8];
    const float* b_fuse  = (const float*)d_in[9];
    const float* w_h1    = (const float*)d_in[10];
    const float* b_h1    = (const float*)d_in[11];
    const float* w_h2    = (const float*)d_in[12];
    const float* b_h2    = (const float*)d_in[13];
    const float* w_h3    = (const float*)d_in[14];
    const float* b_h3    = (const float*)d_in[15];
    const float* w_ev    = (const float*)d_in[16];
    const float* b_ev    = (const float*)d_in[17];
    const float* w_env   = (const float*)d_in[18];
    const float* b_env   = (const float*)d_in[19];

    const int n_nodes  = in_sizes[0] / FIN;       // 100000
    const int E        = in_sizes[1] / 2;         // 3200000
    const int n_graphs = 256;
    const int total    = E + n_nodes;             // edges incl self loops

    // Workspace layout (floats/ints). ~68.5 MB.
    float* ws     = (float*)d_ws;
    float* xh     = ws;                                   // n*64
    float* a_s    = xh   + (size_t)n_nodes * F;           // n*4
    float* a_d    = a_s  + (size_t)n_nodes * HEADS;       // n*4
    float* gat    = a_d  + (size_t)n_nodes * HEADS;       // n*64
    float* sums   = gat  + (size_t)n_nodes * F;           // 256*16
    float* cnts   = sums + (size_t)n_graphs * 16;         // 256
    int*   deg    = (int*)(cnts + n_graphs);              // n
    int*   off    = deg    + n_nodes;                     // n+1
    int*   cursor = off    + n_nodes + 1;                 // n
    int*   srcs   = cursor + n_nodes;                     // E+n
    int*   bsums  = srcs   + total;                       // scan block sums (<=128)

    const int nb = (n_nodes + SCAN_CHUNK - 1) / SCAN_CHUNK;   // 98

    hipMemsetAsync(sums, 0, (size_t)(n_graphs * 16 + n_graphs) * sizeof(float), stream);
    hipMemsetAsync(deg, 0, (size_t)n_nodes * sizeof(int), stream);

    node_prep<<<(n_nodes + 255) / 256, 256, 0, stream>>>(
        x, w_gat, att_src, att_dst, xh, a_s, a_d, n_nodes);

    // CSR build (by dst), rebuilt every call (no cross-call state).
    deg_hist<<<(E + 255) / 256, 256, 0, stream>>>(ei, E, deg);
    scan_p1<<<nb, SCAN_BLOCK, 0, stream>>>(deg, bsums, n_nodes);
    scan_p2<<<1, 128, 0, stream>>>(bsums, nb);
    scan_p3<<<nb, SCAN_BLOCK, 0, stream>>>(deg, bsums, off, cursor, n_nodes, total);
    csr_scatter<<<(total + 255) / 256, 256, 0, stream>>>(ei, E, n_nodes, cursor, srcs);

    long long t2 = (long long)n_nodes * 16;
    gat_agg<<<(int)((t2 + 255) / 256), 256, 0, stream>>>(
        off, srcs, a_s, a_d, xh, gat, n_nodes);

    mlp_pool<<<(n_nodes + 255) / 256, 256, 0, stream>>>(
        gat, b_gat, w_fuse, b_fuse, w_h1, b_h1, w_h2, b_h2, w_h3, b_h3,
        batch, sums, cnts, n_nodes);

    head_kernel<<<(n_graphs + 255) / 256, 256, 0, stream>>>(
        sums, cnts, w_ev, b_ev, w_env, b_env, (float*)d_out, n_graphs);
}

// Round 4
// 1091.784 us; speedup vs baseline: 3.6863x; 1.0109x over previous
//
#include <hip/hip_runtime.h>
#include <hip/hip_bf16.h>

// N=100000 nodes, F_in=20, 4 heads x 16 ch = 64, E=3.2M edges (+N self loops),
// 256 graphs. All fp32.
//
// R3: mlp_pool's h0[64]/t[64] thread-local arrays were never register-promoted
// (VGPR=92 + 53MB scratch WRITE_SIZE regardless of launch_bounds). Fix is
// structural: fuse gather+MLP with 16 threads/node; activations live in a
// small LDS ping-pong buffer (wave-synchronous, no barrier), per-thread state
// is a handful of float4s. Also deletes the 25.6MB gat array (write+read).
#define FIN 20
#define HEADS 4
#define F 64
#define NEG_SLOPE 0.2f
#define SCAN_BLOCK 256
#define SCAN_ITEMS 4
#define SCAN_CHUNK (SCAN_BLOCK * SCAN_ITEMS)   // 1024 elements / block
#define AP 68   // activation row stride (floats): 68*4B=272B, 16B-aligned, bank-skewed

// ---------------------------------------------------------------------------
// Kernel 1: per-node projection xh = x @ w_gat [N,64] + attention scalars.
// ---------------------------------------------------------------------------
__global__ void node_prep(const float* __restrict__ x,
                          const float* __restrict__ w_gat,
                          const float* __restrict__ att_src,
                          const float* __restrict__ att_dst,
                          float* __restrict__ xh,
                          float* __restrict__ a_s,
                          float* __restrict__ a_d,
                          int n_nodes)
{
    __shared__ __align__(16) float w[FIN * F];
    __shared__ float asrc[F];
    __shared__ float adst[F];
    for (int i = threadIdx.x; i < FIN * F; i += blockDim.x) w[i] = w_gat[i];
    if (threadIdx.x < F) {
        asrc[threadIdx.x] = att_src[threadIdx.x];
        adst[threadIdx.x] = att_dst[threadIdx.x];
    }
    __syncthreads();

    int n = blockIdx.x * blockDim.x + threadIdx.x;
    if (n >= n_nodes) return;

    float xv[FIN];
#pragma unroll
    for (int k = 0; k < FIN; ++k) xv[k] = x[(size_t)n * FIN + k];

    float as[HEADS] = {0.f, 0.f, 0.f, 0.f};
    float ad[HEADS] = {0.f, 0.f, 0.f, 0.f};

#pragma unroll
    for (int j4 = 0; j4 < F / 4; ++j4) {
        float4 acc = make_float4(0.f, 0.f, 0.f, 0.f);
#pragma unroll
        for (int k = 0; k < FIN; ++k) {
            float4 w4 = *(const float4*)&w[k * F + j4 * 4];
            acc.x += xv[k] * w4.x;
            acc.y += xv[k] * w4.y;
            acc.z += xv[k] * w4.z;
            acc.w += xv[k] * w4.w;
        }
        *(float4*)&xh[(size_t)n * F + j4 * 4] = acc;
        int h = j4 >> 2;
        int jb = j4 * 4;
        as[h] += acc.x * asrc[jb] + acc.y * asrc[jb + 1] + acc.z * asrc[jb + 2] + acc.w * asrc[jb + 3];
        ad[h] += acc.x * adst[jb] + acc.y * adst[jb + 1] + acc.z * adst[jb + 2] + acc.w * adst[jb + 3];
    }
#pragma unroll
    for (int h = 0; h < HEADS; ++h) {
        a_s[(size_t)n * HEADS + h] = as[h];
        a_d[(size_t)n * HEADS + h] = ad[h];
    }
}

// ---------------------------------------------------------------------------
// CSR build: deg = real-edge histogram (deg memset to 0 beforehand).
// ---------------------------------------------------------------------------
__global__ void deg_hist(const int* __restrict__ ei, int E, int* __restrict__ deg)
{
    int e = blockIdx.x * blockDim.x + threadIdx.x;
    if (e >= E) return;
    atomicAdd(&deg[ei[E + e]], 1);
}

// ---------------------------------------------------------------------------
// 3-phase exclusive scan of deg. Self-loops folded in: off[i]=scan(deg)[i]+i.
// ---------------------------------------------------------------------------
__global__ void scan_p1(const int* __restrict__ deg, int* __restrict__ bsums, int n)
{
    __shared__ int sh[SCAN_BLOCK];
    int base = blockIdx.x * SCAN_CHUNK + threadIdx.x * SCAN_ITEMS;
    int s = 0;
    if (base + SCAN_ITEMS <= n) {
        int4 v = *(const int4*)&deg[base];
        s = v.x + v.y + v.z + v.w;
    } else {
        for (int j = 0; j < SCAN_ITEMS; ++j) { int i = base + j; if (i < n) s += deg[i]; }
    }
    sh[threadIdx.x] = s;
    __syncthreads();
    for (int d = SCAN_BLOCK / 2; d > 0; d >>= 1) {
        if (threadIdx.x < d) sh[threadIdx.x] += sh[threadIdx.x + d];
        __syncthreads();
    }
    if (threadIdx.x == 0) bsums[blockIdx.x] = sh[0];
}

__global__ void scan_p2(int* __restrict__ bsums, int nb)
{
    __shared__ int sh[128];
    int t = threadIdx.x;
    int v = (t < nb) ? bsums[t] : 0;
    sh[t] = v;
    __syncthreads();
    for (int d = 1; d < 128; d <<= 1) {
        int w = (t >= d) ? sh[t - d] : 0;
        __syncthreads();
        sh[t] += w;
        __syncthreads();
    }
    if (t < nb) bsums[t] = (t == 0) ? 0 : sh[t - 1];   // exclusive
}

__global__ void scan_p3(const int* __restrict__ deg, const int* __restrict__ bpre,
                        int* __restrict__ off, int* __restrict__ cursor,
                        int n, int total)
{
    __shared__ int sh[SCAN_BLOCK];
    int t = threadIdx.x;
    int base = blockIdx.x * SCAN_CHUNK + t * SCAN_ITEMS;
    int v[SCAN_ITEMS];
    int s = 0;
    if (base + SCAN_ITEMS <= n) {
        int4 q = *(const int4*)&deg[base];
        v[0] = q.x; v[1] = q.y; v[2] = q.z; v[3] = q.w;
        s = q.x + q.y + q.z + q.w;
    } else {
#pragma unroll
        for (int j = 0; j < SCAN_ITEMS; ++j) { int i = base + j; v[j] = (i < n) ? deg[i] : 0; s += v[j]; }
    }
    sh[t] = s;
    __syncthreads();
    for (int d = 1; d < SCAN_BLOCK; d <<= 1) {
        int w = (t >= d) ? sh[t - d] : 0;
        __syncthreads();
        sh[t] += w;
        __syncthreads();
    }
    int run = bpre[blockIdx.x] + ((t == 0) ? 0 : sh[t - 1]);
#pragma unroll
    for (int j = 0; j < SCAN_ITEMS; ++j) {
        int i = base + j;
        if (i < n) {
            int o = run + i;        // +i accounts for one self-loop per node
            off[i] = o;
            cursor[i] = o;
            run += v[j];
        }
    }
    if (blockIdx.x == 0 && t == 0) off[n] = total;
}

// ---------------------------------------------------------------------------
// CSR scatter: src ids into dst buckets. e in [E,E+N) = self loop.
// ---------------------------------------------------------------------------
__global__ void csr_scatter(const int* __restrict__ ei, int E, int n_nodes,
                            int* __restrict__ cursor, int* __restrict__ srcs)
{
    int e = blockIdx.x * blockDim.x + threadIdx.x;
    int total = E + n_nodes;
    if (e >= total) return;
    int src, dst;
    if (e < E) { src = ei[e]; dst = ei[E + e]; }
    else       { src = dst = e - E; }
    int p = atomicAdd(&cursor[dst], 1);
    srcs[p] = src;
}

// ---------------------------------------------------------------------------
// Fused gather + MLP + pool. 16 threads per node (one node = quarter-wave,
// wave = 4 nodes -> all intra-node LDS traffic is wave-synchronous, no
// barriers). Per-thread state is a few float4s; activations ping-pong through
// LDS rows of AP=68 floats (16B-aligned rows, bank-skewed: (68*nl+k)%32 =
// (4*nl+k)%32 distinct across the wave's 4 nodes).
// ---------------------------------------------------------------------------
__global__ void __launch_bounds__(256)
gat_mlp(const int* __restrict__ off,
        const int* __restrict__ srcs,
        const float* __restrict__ a_s,
        const float* __restrict__ a_d,
        const float* __restrict__ xh,
        const int* __restrict__ batch,
        const float* __restrict__ b_gat,
        const float* __restrict__ w_fuse, const float* __restrict__ b_fuse,
        const float* __restrict__ w_h1, const float* __restrict__ b_h1,
        const float* __restrict__ w_h2, const float* __restrict__ b_h2,
        const float* __restrict__ w_h3, const float* __restrict__ b_h3,
        float* __restrict__ sums, float* __restrict__ cnts,
        int n_nodes)
{
    __shared__ __align__(16) float wf[64 * 64];
    __shared__ __align__(16) float w1[64 * 32];
    __shared__ __align__(16) float w2[32 * 16];
    __shared__ __align__(16) float w3[16 * 16];
    __shared__ __align__(16) float bg[64], bf[64];
    __shared__ __align__(16) float b1[32], b2[16], b3[16];
    __shared__ __align__(16) float actA[16 * AP];
    __shared__ __align__(16) float actB[16 * AP];

    for (int i = threadIdx.x; i < 64 * 64; i += 256) wf[i] = w_fuse[i];
    for (int i = threadIdx.x; i < 64 * 32; i += 256) w1[i] = w_h1[i];
    for (int i = threadIdx.x; i < 32 * 16; i += 256) w2[i] = w_h2[i];
    for (int i = threadIdx.x; i < 16 * 16; i += 256) w3[i] = w_h3[i];
    if (threadIdx.x < 64) { bg[threadIdx.x] = b_gat[threadIdx.x]; bf[threadIdx.x] = b_fuse[threadIdx.x]; }
    else if (threadIdx.x < 96)  b1[threadIdx.x - 64] = b_h1[threadIdx.x - 64];
    else if (threadIdx.x < 112) b2[threadIdx.x - 96] = b_h2[threadIdx.x - 96];
    else if (threadIdx.x < 128) b3[threadIdx.x - 112] = b_h3[threadIdx.x - 112];

    const int node_l = threadIdx.x >> 4;        // 0..15
    const int part   = threadIdx.x & 15;        // 0..15
    const int n      = blockIdx.x * 16 + node_l;
    const bool active = (n < n_nodes);

    // ---- gather phase (per-head softmax-weighted aggregation, z folded) ----
    float4 acc = make_float4(0.f, 0.f, 0.f, 0.f);
    float zacc = 0.f;
    if (active) {
        const int h = part >> 2;
        int kb = off[n];
        int ke = off[n + 1];
        float adh = a_d[n * 4 + h];
        int s = (kb < ke) ? srcs[kb] : 0;
        for (int k = kb; k < ke; ++k) {
            int snext = (k + 1 < ke) ? srcs[k + 1] : 0;   // prefetch index
            float l = a_s[s * 4 + h] + adh;
            l = l > 0.f ? l : NEG_SLOPE * l;
            float e = __expf(l);
            zacc += e;
            float4 v = *(const float4*)&xh[(size_t)s * F + part * 4];
            acc.x += e * v.x; acc.y += e * v.y;
            acc.z += e * v.z; acc.w += e * v.w;
            s = snext;
        }
    }
    __syncthreads();   // weight staging complete (loads overlapped the gather)

    float* rowA = &actA[node_l * AP];
    float* rowB = &actB[node_l * AP];

    // h0 = acc/z + b_gat  -> rowA
    {
        float inv = active ? (1.f / zacc) : 0.f;   // zacc>0 always (self loop)
        float4 b4 = *(const float4*)&bg[part * 4];
        float4 h0;
        h0.x = acc.x * inv + b4.x;
        h0.y = acc.y * inv + b4.y;
        h0.z = acc.z * inv + b4.z;
        h0.w = acc.w * inv + b4.w;
        *(float4*)&rowA[part * 4] = h0;
    }

    // ---- layer 1: 64 -> 64, relu. Thread owns outputs part*4..part*4+3 ----
    {
        float4 a1 = *(const float4*)&bf[part * 4];
#pragma unroll
        for (int k4 = 0; k4 < 16; ++k4) {
            float4 h4 = *(const float4*)&rowA[k4 * 4];
            float4 w0 = *(const float4*)&wf[(k4 * 4 + 0) * 64 + part * 4];
            float4 wq1 = *(const float4*)&wf[(k4 * 4 + 1) * 64 + part * 4];
            float4 wq2 = *(const float4*)&wf[(k4 * 4 + 2) * 64 + part * 4];
            float4 wq3 = *(const float4*)&wf[(k4 * 4 + 3) * 64 + part * 4];
            a1.x += h4.x * w0.x + h4.y * wq1.x + h4.z * wq2.x + h4.w * wq3.x;
            a1.y += h4.x * w0.y + h4.y * wq1.y + h4.z * wq2.y + h4.w * wq3.y;
            a1.z += h4.x * w0.z + h4.y * wq1.z + h4.z * wq2.z + h4.w * wq3.z;
            a1.w += h4.x * w0.w + h4.y * wq1.w + h4.z * wq2.w + h4.w * wq3.w;
        }
        a1.x = a1.x > 0.f ? a1.x : 0.f;
        a1.y = a1.y > 0.f ? a1.y : 0.f;
        a1.z = a1.z > 0.f ? a1.z : 0.f;
        a1.w = a1.w > 0.f ? a1.w : 0.f;
        *(float4*)&rowB[part * 4] = a1;    // t
    }

    // ---- layer 2: 64 -> 32, relu. Thread owns outputs part*2, part*2+1 ----
    {
        float ax = b1[part * 2], ay = b1[part * 2 + 1];
#pragma unroll
        for (int k4 = 0; k4 < 16; ++k4) {
            float4 h4 = *(const float4*)&rowB[k4 * 4];
            float2 wa = *(const float2*)&w1[(k4 * 4 + 0) * 32 + part * 2];
            float2 wb = *(const float2*)&w1[(k4 * 4 + 1) * 32 + part * 2];
            float2 wc = *(const float2*)&w1[(k4 * 4 + 2) * 32 + part * 2];
            float2 wd = *(const float2*)&w1[(k4 * 4 + 3) * 32 + part * 2];
            ax += h4.x * wa.x + h4.y * wb.x + h4.z * wc.x + h4.w * wd.x;
            ay += h4.x * wa.y + h4.y * wb.y + h4.z * wc.y + h4.w * wd.y;
        }
        ax = ax > 0.f ? ax : 0.f;
        ay = ay > 0.f ? ay : 0.f;
        float2 uu; uu.x = ax; uu.y = ay;
        *(float2*)&rowA[part * 2] = uu;    // u in cols 0..31
    }

    // ---- layer 3: 32 -> 16, relu. Thread owns output `part` ----
    {
        float a3 = b2[part];
#pragma unroll
        for (int k4 = 0; k4 < 8; ++k4) {
            float4 h4 = *(const float4*)&rowA[k4 * 4];
            a3 += h4.x * w2[(k4 * 4 + 0) * 16 + part]
                + h4.y * w2[(k4 * 4 + 1) * 16 + part]
                + h4.z * w2[(k4 * 4 + 2) * 16 + part]
                + h4.w * w2[(k4 * 4 + 3) * 16 + part];
        }
        a3 = a3 > 0.f ? a3 : 0.f;
        rowB[part] = a3;                   // v in cols 0..15
    }

    // ---- layer 4: 16 -> 16, relu. Thread owns output `part` ----
    float r;
    {
        float a4 = b3[part];
#pragma unroll
        for (int k4 = 0; k4 < 4; ++k4) {
            float4 h4 = *(const float4*)&rowB[k4 * 4];
            a4 += h4.x * w3[(k4 * 4 + 0) * 16 + part]
                + h4.y * w3[(k4 * 4 + 1) * 16 + part]
                + h4.z * w3[(k4 * 4 + 2) * 16 + part]
                + h4.w * w3[(k4 * 4 + 3) * 16 + part];
        }
        r = a4 > 0.f ? a4 : 0.f;
    }

    // ---- mean-pool accumulation ----
    if (active) {
        int b = batch[n];
        atomicAdd(&sums[b * 16 + part], r);
        if (part == 0) atomicAdd(&cnts[b], 1.0f);
    }
}

// ---------------------------------------------------------------------------
// g = sums / max(cnt,1); two 16->3 heads.
// ---------------------------------------------------------------------------
__global__ void head_kernel(const float* __restrict__ sums,
                            const float* __restrict__ cnts,
                            const float* __restrict__ w_ev, const float* __restrict__ b_ev,
                            const float* __restrict__ w_env, const float* __restrict__ b_env,
                            float* __restrict__ out, int n_graphs)
{
    int g = blockIdx.x * blockDim.x + threadIdx.x;
    if (g >= n_graphs) return;
    float c = cnts[g];
    c = c > 1.f ? c : 1.f;
    float gg[16];
#pragma unroll
    for (int j = 0; j < 16; ++j) gg[j] = sums[(size_t)g * 16 + j] / c;
#pragma unroll
    for (int j = 0; j < 3; ++j) {
        float a = b_ev[j];
#pragma unroll
        for (int k = 0; k < 16; ++k) a += gg[k] * w_ev[k * 3 + j];
        out[(size_t)g * 3 + j] = a;
    }
#pragma unroll
    for (int j = 0; j < 3; ++j) {
        float a = b_env[j];
#pragma unroll
        for (int k = 0; k < 16; ++k) a += gg[k] * w_env[k * 3 + j];
        out[(size_t)n_graphs * 3 + (size_t)g * 3 + j] = a;
    }
}

// ---------------------------------------------------------------------------
extern "C" void kernel_launch(void* const* d_in, const int* in_sizes, int n_in,
                              void* d_out, int out_size, void* d_ws, size_t ws_size,
                              hipStream_t stream)
{
    const float* x       = (const float*)d_in[0];
    const int*   ei      = (const int*)d_in[1];
    const int*   batch   = (const int*)d_in[2];
    const float* w_gat   = (const float*)d_in[4];
    const float* att_src = (const float*)d_in[5];
    const float* att_dst = (const float*)d_in[6];
    const float* b_gat   = (const float*)d_in[7];
    const float* w_fuse  = (const float*)d_in[8];
    const float* b_fuse  = (const float*)d_in[9];
    const float* w_h1    = (const float*)d_in[10];
    const float* b_h1    = (const float*)d_in[11];
    const float* w_h2    = (const float*)d_in[12];
    const float* b_h2    = (const float*)d_in[13];
    const float* w_h3    = (const float*)d_in[14];
    const float* b_h3    = (const float*)d_in[15];
    const float* w_ev    = (const float*)d_in[16];
    const float* b_ev    = (const float*)d_in[17];
    const float* w_env   = (const float*)d_in[18];
    const float* b_env   = (const float*)d_in[19];

    const int n_nodes  = in_sizes[0] / FIN;       // 100000
    const int E        = in_sizes[1] / 2;         // 3200000
    const int n_graphs = 256;
    const int total    = E + n_nodes;             // edges incl self loops

    // Workspace layout (floats/ints). ~43 MB.
    float* ws     = (float*)d_ws;
    float* xh     = ws;                                   // n*64
    float* a_s    = xh   + (size_t)n_nodes * F;           // n*4
    float* a_d    = a_s  + (size_t)n_nodes * HEADS;       // n*4
    float* sums   = a_d  + (size_t)n_nodes * HEADS;       // 256*16
    float* cnts   = sums + (size_t)n_graphs * 16;         // 256
    int*   deg    = (int*)(cnts + n_graphs);              // n
    int*   off    = deg    + n_nodes;                     // n+1
    int*   cursor = off    + n_nodes + 1;                 // n
    int*   srcs   = cursor + n_nodes;                     // E+n
    int*   bsums  = srcs   + total;                       // scan block sums (<=128)

    const int nb = (n_nodes + SCAN_CHUNK - 1) / SCAN_CHUNK;   // 98

    hipMemsetAsync(sums, 0, (size_t)(n_graphs * 16 + n_graphs) * sizeof(float), stream);
    hipMemsetAsync(deg, 0, (size_t)n_nodes * sizeof(int), stream);

    node_prep<<<(n_nodes + 255) / 256, 256, 0, stream>>>(
        x, w_gat, att_src, att_dst, xh, a_s, a_d, n_nodes);

    // CSR build (by dst), rebuilt every call (no cross-call state).
    deg_hist<<<(E + 255) / 256, 256, 0, stream>>>(ei, E, deg);
    scan_p1<<<nb, SCAN_BLOCK, 0, stream>>>(deg, bsums, n_nodes);
    scan_p2<<<1, 128, 0, stream>>>(bsums, nb);
    scan_p3<<<nb, SCAN_BLOCK, 0, stream>>>(deg, bsums, off, cursor, n_nodes, total);
    csr_scatter<<<(total + 255) / 256, 256, 0, stream>>>(ei, E, n_nodes, cursor, srcs);

    gat_mlp<<<(n_nodes + 15) / 16, 256, 0, stream>>>(
        off, srcs, a_s, a_d, xh, batch, b_gat,
        w_fuse, b_fuse, w_h1, b_h1, w_h2, b_h2, w_h3, b_h3,
        sums, cnts, n_nodes);

    head_kernel<<<(n_graphs + 255) / 256, 256, 0, stream>>>(
        sums, cnts, w_ev, b_ev, w_env, b_env, (float*)d_out, n_graphs);
}

// Round 5
// 1031.152 us; speedup vs baseline: 3.9030x; 1.0588x over previous
//
#include <hip/hip_runtime.h>
#include <hip/hip_bf16.h>
#include <hip/hip_fp16.h>

// N=100000 nodes, F_in=20, 4 heads x 16 ch = 64, E=3.2M edges (+N self loops),
// 256 graphs. All fp32 in/out.
//
// R4: gat_mlp was gather-bound (FETCH 455MB, VALU 10%): 256B fp32 xh row per
// edge = 4 cachelines, missing L2 to LLC. (a) xh stored fp16 -> 128B row
// (2 lines), fp32 accumulate (err ~6e-4 << 4.4e-3 threshold). (b) gather
// reads srcs in 16-edge chunks (1 dword/lane, __shfl broadcast) with fully
// unrolled inner body -> 16 independent gather loads in flight per chunk.
#define FIN 20
#define HEADS 4
#define F 64
#define NEG_SLOPE 0.2f
#define SCAN_BLOCK 256
#define SCAN_ITEMS 4
#define SCAN_CHUNK (SCAN_BLOCK * SCAN_ITEMS)   // 1024 elements / block
#define AP 68   // activation row stride (floats)

// ---------------------------------------------------------------------------
// Kernel 1: per-node projection xh(half) = x @ w_gat [N,64] + attn scalars.
// ---------------------------------------------------------------------------
__global__ void node_prep(const float* __restrict__ x,
                          const float* __restrict__ w_gat,
                          const float* __restrict__ att_src,
                          const float* __restrict__ att_dst,
                          __half* __restrict__ xh,
                          float* __restrict__ a_s,
                          float* __restrict__ a_d,
                          int n_nodes)
{
    __shared__ __align__(16) float w[FIN * F];
    __shared__ float asrc[F];
    __shared__ float adst[F];
    for (int i = threadIdx.x; i < FIN * F; i += blockDim.x) w[i] = w_gat[i];
    if (threadIdx.x < F) {
        asrc[threadIdx.x] = att_src[threadIdx.x];
        adst[threadIdx.x] = att_dst[threadIdx.x];
    }
    __syncthreads();

    int n = blockIdx.x * blockDim.x + threadIdx.x;
    if (n >= n_nodes) return;

    float xv[FIN];
#pragma unroll
    for (int k = 0; k < FIN; ++k) xv[k] = x[(size_t)n * FIN + k];

    float as[HEADS] = {0.f, 0.f, 0.f, 0.f};
    float ad[HEADS] = {0.f, 0.f, 0.f, 0.f};

#pragma unroll
    for (int j4 = 0; j4 < F / 4; ++j4) {
        float4 acc = make_float4(0.f, 0.f, 0.f, 0.f);
#pragma unroll
        for (int k = 0; k < FIN; ++k) {
            float4 w4 = *(const float4*)&w[k * F + j4 * 4];
            acc.x += xv[k] * w4.x;
            acc.y += xv[k] * w4.y;
            acc.z += xv[k] * w4.z;
            acc.w += xv[k] * w4.w;
        }
        __half2 p0 = __floats2half2_rn(acc.x, acc.y);
        __half2 p1 = __floats2half2_rn(acc.z, acc.w);
        float2 st;
        ((__half2*)&st)[0] = p0;
        ((__half2*)&st)[1] = p1;
        *(float2*)&xh[(size_t)n * F + j4 * 4] = st;

        int h = j4 >> 2;
        int jb = j4 * 4;
        as[h] += acc.x * asrc[jb] + acc.y * asrc[jb + 1] + acc.z * asrc[jb + 2] + acc.w * asrc[jb + 3];
        ad[h] += acc.x * adst[jb] + acc.y * adst[jb + 1] + acc.z * adst[jb + 2] + acc.w * adst[jb + 3];
    }
#pragma unroll
    for (int h = 0; h < HEADS; ++h) {
        a_s[(size_t)n * HEADS + h] = as[h];
        a_d[(size_t)n * HEADS + h] = ad[h];
    }
}

// ---------------------------------------------------------------------------
// CSR build: deg = real-edge histogram (deg memset to 0 beforehand).
// ---------------------------------------------------------------------------
__global__ void deg_hist(const int* __restrict__ ei, int E, int* __restrict__ deg)
{
    int e = blockIdx.x * blockDim.x + threadIdx.x;
    if (e >= E) return;
    atomicAdd(&deg[ei[E + e]], 1);
}

// ---------------------------------------------------------------------------
// 3-phase exclusive scan of deg. Self-loops folded in: off[i]=scan(deg)[i]+i.
// ---------------------------------------------------------------------------
__global__ void scan_p1(const int* __restrict__ deg, int* __restrict__ bsums, int n)
{
    __shared__ int sh[SCAN_BLOCK];
    int base = blockIdx.x * SCAN_CHUNK + threadIdx.x * SCAN_ITEMS;
    int s = 0;
    if (base + SCAN_ITEMS <= n) {
        int4 v = *(const int4*)&deg[base];
        s = v.x + v.y + v.z + v.w;
    } else {
        for (int j = 0; j < SCAN_ITEMS; ++j) { int i = base + j; if (i < n) s += deg[i]; }
    }
    sh[threadIdx.x] = s;
    __syncthreads();
    for (int d = SCAN_BLOCK / 2; d > 0; d >>= 1) {
        if (threadIdx.x < d) sh[threadIdx.x] += sh[threadIdx.x + d];
        __syncthreads();
    }
    if (threadIdx.x == 0) bsums[blockIdx.x] = sh[0];
}

__global__ void scan_p2(int* __restrict__ bsums, int nb)
{
    __shared__ int sh[128];
    int t = threadIdx.x;
    int v = (t < nb) ? bsums[t] : 0;
    sh[t] = v;
    __syncthreads();
    for (int d = 1; d < 128; d <<= 1) {
        int w = (t >= d) ? sh[t - d] : 0;
        __syncthreads();
        sh[t] += w;
        __syncthreads();
    }
    if (t < nb) bsums[t] = (t == 0) ? 0 : sh[t - 1];   // exclusive
}

__global__ void scan_p3(const int* __restrict__ deg, const int* __restrict__ bpre,
                        int* __restrict__ off, int* __restrict__ cursor,
                        int n, int total)
{
    __shared__ int sh[SCAN_BLOCK];
    int t = threadIdx.x;
    int base = blockIdx.x * SCAN_CHUNK + t * SCAN_ITEMS;
    int v[SCAN_ITEMS];
    int s = 0;
    if (base + SCAN_ITEMS <= n) {
        int4 q = *(const int4*)&deg[base];
        v[0] = q.x; v[1] = q.y; v[2] = q.z; v[3] = q.w;
        s = q.x + q.y + q.z + q.w;
    } else {
#pragma unroll
        for (int j = 0; j < SCAN_ITEMS; ++j) { int i = base + j; v[j] = (i < n) ? deg[i] : 0; s += v[j]; }
    }
    sh[t] = s;
    __syncthreads();
    for (int d = 1; d < SCAN_BLOCK; d <<= 1) {
        int w = (t >= d) ? sh[t - d] : 0;
        __syncthreads();
        sh[t] += w;
        __syncthreads();
    }
    int run = bpre[blockIdx.x] + ((t == 0) ? 0 : sh[t - 1]);
#pragma unroll
    for (int j = 0; j < SCAN_ITEMS; ++j) {
        int i = base + j;
        if (i < n) {
            int o = run + i;        // +i accounts for one self-loop per node
            off[i] = o;
            cursor[i] = o;
            run += v[j];
        }
    }
    if (blockIdx.x == 0 && t == 0) off[n] = total;
}

// ---------------------------------------------------------------------------
// CSR scatter: src ids into dst buckets. e in [E,E+N) = self loop.
// ---------------------------------------------------------------------------
__global__ void csr_scatter(const int* __restrict__ ei, int E, int n_nodes,
                            int* __restrict__ cursor, int* __restrict__ srcs)
{
    int e = blockIdx.x * blockDim.x + threadIdx.x;
    int total = E + n_nodes;
    if (e >= total) return;
    int src, dst;
    if (e < E) { src = ei[e]; dst = ei[E + e]; }
    else       { src = dst = e - E; }
    int p = atomicAdd(&cursor[dst], 1);
    srcs[p] = src;
}

// ---------------------------------------------------------------------------
// Fused gather + MLP + pool. 16 threads per node. Gather reads srcs in
// 16-edge chunks: one dword per lane, __shfl broadcast, fully unrolled inner
// body so the 16 a_s/xh loads issue independently (deep vmcnt pipelining).
// ---------------------------------------------------------------------------
__global__ void __launch_bounds__(256)
gat_mlp(const int* __restrict__ off,
        const int* __restrict__ srcs,
        const float* __restrict__ a_s,
        const float* __restrict__ a_d,
        const __half* __restrict__ xh,
        const int* __restrict__ batch,
        const float* __restrict__ b_gat,
        const float* __restrict__ w_fuse, const float* __restrict__ b_fuse,
        const float* __restrict__ w_h1, const float* __restrict__ b_h1,
        const float* __restrict__ w_h2, const float* __restrict__ b_h2,
        const float* __restrict__ w_h3, const float* __restrict__ b_h3,
        float* __restrict__ sums, float* __restrict__ cnts,
        int n_nodes)
{
    __shared__ __align__(16) float wf[64 * 64];
    __shared__ __align__(16) float w1[64 * 32];
    __shared__ __align__(16) float w2[32 * 16];
    __shared__ __align__(16) float w3[16 * 16];
    __shared__ __align__(16) float bg[64], bf[64];
    __shared__ __align__(16) float b1[32], b2[16], b3[16];
    __shared__ __align__(16) float actA[16 * AP];
    __shared__ __align__(16) float actB[16 * AP];

    for (int i = threadIdx.x; i < 64 * 64; i += 256) wf[i] = w_fuse[i];
    for (int i = threadIdx.x; i < 64 * 32; i += 256) w1[i] = w_h1[i];
    for (int i = threadIdx.x; i < 32 * 16; i += 256) w2[i] = w_h2[i];
    for (int i = threadIdx.x; i < 16 * 16; i += 256) w3[i] = w_h3[i];
    if (threadIdx.x < 64) { bg[threadIdx.x] = b_gat[threadIdx.x]; bf[threadIdx.x] = b_fuse[threadIdx.x]; }
    else if (threadIdx.x < 96)  b1[threadIdx.x - 64] = b_h1[threadIdx.x - 64];
    else if (threadIdx.x < 112) b2[threadIdx.x - 96] = b_h2[threadIdx.x - 96];
    else if (threadIdx.x < 128) b3[threadIdx.x - 112] = b_h3[threadIdx.x - 112];

    const int node_l = threadIdx.x >> 4;        // 0..15 node within block
    const int part   = threadIdx.x & 15;        // 0..15 channel group
    const int nw     = node_l & 3;              // node within wave (0..3)
    const int n      = blockIdx.x * 16 + node_l;
    const bool active = (n < n_nodes);

    // ---- gather phase ----
    float4 acc = make_float4(0.f, 0.f, 0.f, 0.f);
    float zacc = 0.f;
    if (active) {
        const int h = part >> 2;
        int kb = off[n];
        int ke = off[n + 1];
        float adh = a_d[n * 4 + h];
        for (int base = kb; base < ke; base += 16) {
            int idx = base + part;
            int my_s = (idx < ke) ? srcs[idx] : 0;
#pragma unroll
            for (int j = 0; j < 16; ++j) {
                if (base + j < ke) {
                    int s = __shfl(my_s, nw * 16 + j, 64);
                    float l = a_s[s * 4 + h] + adh;
                    l = l > 0.f ? l : NEG_SLOPE * l;
                    float e = __expf(l);
                    zacc += e;
                    float2 raw = *(const float2*)&xh[(size_t)s * F + part * 4];
                    float2 lo = __half22float2(((const __half2*)&raw)[0]);
                    float2 hi = __half22float2(((const __half2*)&raw)[1]);
                    acc.x += e * lo.x; acc.y += e * lo.y;
                    acc.z += e * hi.x; acc.w += e * hi.y;
                }
            }
        }
    }
    __syncthreads();   // weight staging complete (overlapped with gather)

    float* rowA = &actA[node_l * AP];
    float* rowB = &actB[node_l * AP];

    // h0 = acc/z + b_gat  -> rowA
    {
        float inv = active ? (1.f / zacc) : 0.f;   // zacc>0 always (self loop)
        float4 b4 = *(const float4*)&bg[part * 4];
        float4 h0;
        h0.x = acc.x * inv + b4.x;
        h0.y = acc.y * inv + b4.y;
        h0.z = acc.z * inv + b4.z;
        h0.w = acc.w * inv + b4.w;
        *(float4*)&rowA[part * 4] = h0;
    }

    // ---- layer 1: 64 -> 64, relu ----
    {
        float4 a1 = *(const float4*)&bf[part * 4];
#pragma unroll
        for (int k4 = 0; k4 < 16; ++k4) {
            float4 h4 = *(const float4*)&rowA[k4 * 4];
            float4 w0 = *(const float4*)&wf[(k4 * 4 + 0) * 64 + part * 4];
            float4 wq1 = *(const float4*)&wf[(k4 * 4 + 1) * 64 + part * 4];
            float4 wq2 = *(const float4*)&wf[(k4 * 4 + 2) * 64 + part * 4];
            float4 wq3 = *(const float4*)&wf[(k4 * 4 + 3) * 64 + part * 4];
            a1.x += h4.x * w0.x + h4.y * wq1.x + h4.z * wq2.x + h4.w * wq3.x;
            a1.y += h4.x * w0.y + h4.y * wq1.y + h4.z * wq2.y + h4.w * wq3.y;
            a1.z += h4.x * w0.z + h4.y * wq1.z + h4.z * wq2.z + h4.w * wq3.z;
            a1.w += h4.x * w0.w + h4.y * wq1.w + h4.z * wq2.w + h4.w * wq3.w;
        }
        a1.x = a1.x > 0.f ? a1.x : 0.f;
        a1.y = a1.y > 0.f ? a1.y : 0.f;
        a1.z = a1.z > 0.f ? a1.z : 0.f;
        a1.w = a1.w > 0.f ? a1.w : 0.f;
        *(float4*)&rowB[part * 4] = a1;    // t
    }

    // ---- layer 2: 64 -> 32, relu ----
    {
        float ax = b1[part * 2], ay = b1[part * 2 + 1];
#pragma unroll
        for (int k4 = 0; k4 < 16; ++k4) {
            float4 h4 = *(const float4*)&rowB[k4 * 4];
            float2 wa = *(const float2*)&w1[(k4 * 4 + 0) * 32 + part * 2];
            float2 wb = *(const float2*)&w1[(k4 * 4 + 1) * 32 + part * 2];
            float2 wc = *(const float2*)&w1[(k4 * 4 + 2) * 32 + part * 2];
            float2 wd = *(const float2*)&w1[(k4 * 4 + 3) * 32 + part * 2];
            ax += h4.x * wa.x + h4.y * wb.x + h4.z * wc.x + h4.w * wd.x;
            ay += h4.x * wa.y + h4.y * wb.y + h4.z * wc.y + h4.w * wd.y;
        }
        ax = ax > 0.f ? ax : 0.f;
        ay = ay > 0.f ? ay : 0.f;
        float2 uu; uu.x = ax; uu.y = ay;
        *(float2*)&rowA[part * 2] = uu;    // u in cols 0..31
    }

    // ---- layer 3: 32 -> 16, relu ----
    {
        float a3 = b2[part];
#pragma unroll
        for (int k4 = 0; k4 < 8; ++k4) {
            float4 h4 = *(const float4*)&rowA[k4 * 4];
            a3 += h4.x * w2[(k4 * 4 + 0) * 16 + part]
                + h4.y * w2[(k4 * 4 + 1) * 16 + part]
                + h4.z * w2[(k4 * 4 + 2) * 16 + part]
                + h4.w * w2[(k4 * 4 + 3) * 16 + part];
        }
        a3 = a3 > 0.f ? a3 : 0.f;
        rowB[part] = a3;                   // v in cols 0..15
    }

    // ---- layer 4: 16 -> 16, relu ----
    float r;
    {
        float a4 = b3[part];
#pragma unroll
        for (int k4 = 0; k4 < 4; ++k4) {
            float4 h4 = *(const float4*)&rowB[k4 * 4];
            a4 += h4.x * w3[(k4 * 4 + 0) * 16 + part]
                + h4.y * w3[(k4 * 4 + 1) * 16 + part]
                + h4.z * w3[(k4 * 4 + 2) * 16 + part]
                + h4.w * w3[(k4 * 4 + 3) * 16 + part];
        }
        r = a4 > 0.f ? a4 : 0.f;
    }

    // ---- mean-pool accumulation ----
    if (active) {
        int b = batch[n];
        atomicAdd(&sums[b * 16 + part], r);
        if (part == 0) atomicAdd(&cnts[b], 1.0f);
    }
}

// ---------------------------------------------------------------------------
// g = sums / max(cnt,1); two 16->3 heads.
// ---------------------------------------------------------------------------
__global__ void head_kernel(const float* __restrict__ sums,
                            const float* __restrict__ cnts,
                            const float* __restrict__ w_ev, const float* __restrict__ b_ev,
                            const float* __restrict__ w_env, const float* __restrict__ b_env,
                            float* __restrict__ out, int n_graphs)
{
    int g = blockIdx.x * blockDim.x + threadIdx.x;
    if (g >= n_graphs) return;
    float c = cnts[g];
    c = c > 1.f ? c : 1.f;
    float gg[16];
#pragma unroll
    for (int j = 0; j < 16; ++j) gg[j] = sums[(size_t)g * 16 + j] / c;
#pragma unroll
    for (int j = 0; j < 3; ++j) {
        float a = b_ev[j];
#pragma unroll
        for (int k = 0; k < 16; ++k) a += gg[k] * w_ev[k * 3 + j];
        out[(size_t)g * 3 + j] = a;
    }
#pragma unroll
    for (int j = 0; j < 3; ++j) {
        float a = b_env[j];
#pragma unroll
        for (int k = 0; k < 16; ++k) a += gg[k] * w_env[k * 3 + j];
        out[(size_t)n_graphs * 3 + (size_t)g * 3 + j] = a;
    }
}

// ---------------------------------------------------------------------------
extern "C" void kernel_launch(void* const* d_in, const int* in_sizes, int n_in,
                              void* d_out, int out_size, void* d_ws, size_t ws_size,
                              hipStream_t stream)
{
    const float* x       = (const float*)d_in[0];
    const int*   ei      = (const int*)d_in[1];
    const int*   batch   = (const int*)d_in[2];
    const float* w_gat   = (const float*)d_in[4];
    const float* att_src = (const float*)d_in[5];
    const float* att_dst = (const float*)d_in[6];
    const float* b_gat   = (const float*)d_in[7];
    const float* w_fuse  = (const float*)d_in[8];
    const float* b_fuse  = (const float*)d_in[9];
    const float* w_h1    = (const float*)d_in[10];
    const float* b_h1    = (const float*)d_in[11];
    const float* w_h2    = (const float*)d_in[12];
    const float* b_h2    = (const float*)d_in[13];
    const float* w_h3    = (const float*)d_in[14];
    const float* b_h3    = (const float*)d_in[15];
    const float* w_ev    = (const float*)d_in[16];
    const float* b_ev    = (const float*)d_in[17];
    const float* w_env   = (const float*)d_in[18];
    const float* b_env   = (const float*)d_in[19];

    const int n_nodes  = in_sizes[0] / FIN;       // 100000
    const int E        = in_sizes[1] / 2;         // 3200000
    const int n_graphs = 256;
    const int total    = E + n_nodes;             // edges incl self loops

    // Workspace layout. xh is fp16 now (n*64 halves = n*32 float slots).
    float* ws     = (float*)d_ws;
    __half* xh    = (__half*)ws;                          // n*64 halves
    float* a_s    = ws   + (size_t)n_nodes * 32;          // n*4
    float* a_d    = a_s  + (size_t)n_nodes * HEADS;       // n*4
    float* sums   = a_d  + (size_t)n_nodes * HEADS;       // 256*16
    float* cnts   = sums + (size_t)n_graphs * 16;         // 256
    int*   deg    = (int*)(cnts + n_graphs);              // n
    int*   off    = deg    + n_nodes;                     // n+1
    int*   cursor = off    + n_nodes + 1;                 // n
    int*   srcs   = cursor + n_nodes;                     // E+n
    int*   bsums  = srcs   + total;                       // scan block sums (<=128)

    const int nb = (n_nodes + SCAN_CHUNK - 1) / SCAN_CHUNK;   // 98

    hipMemsetAsync(sums, 0, (size_t)(n_graphs * 16 + n_graphs) * sizeof(float), stream);
    hipMemsetAsync(deg, 0, (size_t)n_nodes * sizeof(int), stream);

    node_prep<<<(n_nodes + 255) / 256, 256, 0, stream>>>(
        x, w_gat, att_src, att_dst, xh, a_s, a_d, n_nodes);

    // CSR build (by dst), rebuilt every call (no cross-call state).
    deg_hist<<<(E + 255) / 256, 256, 0, stream>>>(ei, E, deg);
    scan_p1<<<nb, SCAN_BLOCK, 0, stream>>>(deg, bsums, n_nodes);
    scan_p2<<<1, 128, 0, stream>>>(bsums, nb);
    scan_p3<<<nb, SCAN_BLOCK, 0, stream>>>(deg, bsums, off, cursor, n_nodes, total);
    csr_scatter<<<(total + 255) / 256, 256, 0, stream>>>(ei, E, n_nodes, cursor, srcs);

    gat_mlp<<<(n_nodes + 15) / 16, 256, 0, stream>>>(
        off, srcs, a_s, a_d, xh, batch, b_gat,
        w_fuse, b_fuse, w_h1, b_h1, w_h2, b_h2, w_h3, b_h3,
        sums, cnts, n_nodes);

    head_kernel<<<(n_graphs + 255) / 256, 256, 0, stream>>>(
        sums, cnts, w_ev, b_ev, w_env, b_env, (float*)d_out, n_graphs);
}

// Round 6
// 928.068 us; speedup vs baseline: 4.3365x; 1.1111x over previous
//
#include <hip/hip_runtime.h>
#include <hip/hip_bf16.h>
#include <hip/hip_fp16.h>

// N=100000 nodes, F_in=20, 4 heads x 16 ch = 64, E=3.2M edges (+N self loops),
// 256 graphs. All fp32 in/out.
//
// R5: R4's fused gat_mlp was latency-bound (Occ 36% from 37KB LDS, branchy
// per-edge loop blocking load hoisting; halving bytes only gained 10%).
// Unfuse: gat_gather = zero-LDS, 8 lanes/node (8 edge streams/wave),
// branch-free clamped chunks -> all loads hoist, occupancy ~2.5x.
// mlp_pool2 = the proven 16-lane/node LDS MLP reading h0[n,64] fp32.
#define FIN 20
#define HEADS 4
#define F 64
#define NEG_SLOPE 0.2f
#define SCAN_BLOCK 256
#define SCAN_ITEMS 4
#define SCAN_CHUNK (SCAN_BLOCK * SCAN_ITEMS)   // 1024 elements / block
#define AP 68   // activation row stride (floats)

// ---------------------------------------------------------------------------
// Kernel 1: per-node projection xh(half) = x @ w_gat [N,64] + attn scalars.
// ---------------------------------------------------------------------------
__global__ void node_prep(const float* __restrict__ x,
                          const float* __restrict__ w_gat,
                          const float* __restrict__ att_src,
                          const float* __restrict__ att_dst,
                          __half* __restrict__ xh,
                          float* __restrict__ a_s,
                          float* __restrict__ a_d,
                          int n_nodes)
{
    __shared__ __align__(16) float w[FIN * F];
    __shared__ float asrc[F];
    __shared__ float adst[F];
    for (int i = threadIdx.x; i < FIN * F; i += blockDim.x) w[i] = w_gat[i];
    if (threadIdx.x < F) {
        asrc[threadIdx.x] = att_src[threadIdx.x];
        adst[threadIdx.x] = att_dst[threadIdx.x];
    }
    __syncthreads();

    int n = blockIdx.x * blockDim.x + threadIdx.x;
    if (n >= n_nodes) return;

    float xv[FIN];
#pragma unroll
    for (int q = 0; q < FIN / 4; ++q) {
        float4 x4 = *(const float4*)&x[(size_t)n * FIN + q * 4];
        xv[q * 4 + 0] = x4.x; xv[q * 4 + 1] = x4.y;
        xv[q * 4 + 2] = x4.z; xv[q * 4 + 3] = x4.w;
    }

    float as[HEADS] = {0.f, 0.f, 0.f, 0.f};
    float ad[HEADS] = {0.f, 0.f, 0.f, 0.f};

#pragma unroll
    for (int j4 = 0; j4 < F / 4; ++j4) {
        float4 acc = make_float4(0.f, 0.f, 0.f, 0.f);
#pragma unroll
        for (int k = 0; k < FIN; ++k) {
            float4 w4 = *(const float4*)&w[k * F + j4 * 4];
            acc.x += xv[k] * w4.x;
            acc.y += xv[k] * w4.y;
            acc.z += xv[k] * w4.z;
            acc.w += xv[k] * w4.w;
        }
        __half2 p0 = __floats2half2_rn(acc.x, acc.y);
        __half2 p1 = __floats2half2_rn(acc.z, acc.w);
        float2 st;
        ((__half2*)&st)[0] = p0;
        ((__half2*)&st)[1] = p1;
        *(float2*)&xh[(size_t)n * F + j4 * 4] = st;

        int h = j4 >> 2;
        int jb = j4 * 4;
        as[h] += acc.x * asrc[jb] + acc.y * asrc[jb + 1] + acc.z * asrc[jb + 2] + acc.w * asrc[jb + 3];
        ad[h] += acc.x * adst[jb] + acc.y * adst[jb + 1] + acc.z * adst[jb + 2] + acc.w * adst[jb + 3];
    }
#pragma unroll
    for (int h = 0; h < HEADS; ++h) {
        a_s[(size_t)n * HEADS + h] = as[h];
        a_d[(size_t)n * HEADS + h] = ad[h];
    }
}

// ---------------------------------------------------------------------------
// CSR build: deg = real-edge histogram (deg memset to 0 beforehand).
// ---------------------------------------------------------------------------
__global__ void deg_hist(const int* __restrict__ ei, int E, int* __restrict__ deg)
{
    int e = blockIdx.x * blockDim.x + threadIdx.x;
    if (e >= E) return;
    atomicAdd(&deg[ei[E + e]], 1);
}

// ---------------------------------------------------------------------------
// 3-phase exclusive scan of deg. Self-loops folded in: off[i]=scan(deg)[i]+i.
// ---------------------------------------------------------------------------
__global__ void scan_p1(const int* __restrict__ deg, int* __restrict__ bsums, int n)
{
    __shared__ int sh[SCAN_BLOCK];
    int base = blockIdx.x * SCAN_CHUNK + threadIdx.x * SCAN_ITEMS;
    int s = 0;
    if (base + SCAN_ITEMS <= n) {
        int4 v = *(const int4*)&deg[base];
        s = v.x + v.y + v.z + v.w;
    } else {
        for (int j = 0; j < SCAN_ITEMS; ++j) { int i = base + j; if (i < n) s += deg[i]; }
    }
    sh[threadIdx.x] = s;
    __syncthreads();
    for (int d = SCAN_BLOCK / 2; d > 0; d >>= 1) {
        if (threadIdx.x < d) sh[threadIdx.x] += sh[threadIdx.x + d];
        __syncthreads();
    }
    if (threadIdx.x == 0) bsums[blockIdx.x] = sh[0];
}

__global__ void scan_p2(int* __restrict__ bsums, int nb)
{
    __shared__ int sh[128];
    int t = threadIdx.x;
    int v = (t < nb) ? bsums[t] : 0;
    sh[t] = v;
    __syncthreads();
    for (int d = 1; d < 128; d <<= 1) {
        int w = (t >= d) ? sh[t - d] : 0;
        __syncthreads();
        sh[t] += w;
        __syncthreads();
    }
    if (t < nb) bsums[t] = (t == 0) ? 0 : sh[t - 1];   // exclusive
}

__global__ void scan_p3(const int* __restrict__ deg, const int* __restrict__ bpre,
                        int* __restrict__ off, int* __restrict__ cursor,
                        int n, int total)
{
    __shared__ int sh[SCAN_BLOCK];
    int t = threadIdx.x;
    int base = blockIdx.x * SCAN_CHUNK + t * SCAN_ITEMS;
    int v[SCAN_ITEMS];
    int s = 0;
    if (base + SCAN_ITEMS <= n) {
        int4 q = *(const int4*)&deg[base];
        v[0] = q.x; v[1] = q.y; v[2] = q.z; v[3] = q.w;
        s = q.x + q.y + q.z + q.w;
    } else {
#pragma unroll
        for (int j = 0; j < SCAN_ITEMS; ++j) { int i = base + j; v[j] = (i < n) ? deg[i] : 0; s += v[j]; }
    }
    sh[t] = s;
    __syncthreads();
    for (int d = 1; d < SCAN_BLOCK; d <<= 1) {
        int w = (t >= d) ? sh[t - d] : 0;
        __syncthreads();
        sh[t] += w;
        __syncthreads();
    }
    int run = bpre[blockIdx.x] + ((t == 0) ? 0 : sh[t - 1]);
#pragma unroll
    for (int j = 0; j < SCAN_ITEMS; ++j) {
        int i = base + j;
        if (i < n) {
            int o = run + i;        // +i accounts for one self-loop per node
            off[i] = o;
            cursor[i] = o;
            run += v[j];
        }
    }
    if (blockIdx.x == 0 && t == 0) off[n] = total;
}

// ---------------------------------------------------------------------------
// CSR scatter: src ids into dst buckets. e in [E,E+N) = self loop.
// ---------------------------------------------------------------------------
__global__ void csr_scatter(const int* __restrict__ ei, int E, int n_nodes,
                            int* __restrict__ cursor, int* __restrict__ srcs)
{
    int e = blockIdx.x * blockDim.x + threadIdx.x;
    int total = E + n_nodes;
    if (e >= total) return;
    int src, dst;
    if (e < E) { src = ei[e]; dst = ei[E + e]; }
    else       { src = dst = e - E; }
    int p = atomicAdd(&cursor[dst], 1);
    srcs[p] = src;
}

// ---------------------------------------------------------------------------
// Gather: 8 lanes per node (8 nodes/wave -> 8 independent edge streams per
// wave). Lane `part` owns channels part*8..part*8+7 (head = part>>1).
// Inner chunk of 8 edges is branch-free: srcs index clamped to ke-1, invalid
// edges get weight 0 via cndmask -> all 8 xh + 8 a_s loads hoist and overlap.
// Writes h0 = acc/z + b_gat (normalization + bias folded). No LDS -> high occ.
// ---------------------------------------------------------------------------
__global__ void __launch_bounds__(256)
gat_gather(const int* __restrict__ off,
           const int* __restrict__ srcs,
           const float* __restrict__ a_s,
           const float* __restrict__ a_d,
           const __half* __restrict__ xh,
           const float* __restrict__ b_gat,
           float* __restrict__ h0out,
           int n_nodes)
{
    int tid = blockIdx.x * 256 + threadIdx.x;
    int n = tid >> 3;
    int part = tid & 7;
    if (n >= n_nodes) return;          // grid exact for N=100000; safe anyway
    const int h = part >> 1;
    const int g8 = (threadIdx.x & 63) >> 3;   // node slot within wave (0..7)

    int kb = off[n];
    int ke = off[n + 1];
    float adh = a_d[n * 4 + h];

    float acc[8] = {0.f, 0.f, 0.f, 0.f, 0.f, 0.f, 0.f, 0.f};
    float zacc = 0.f;

    for (int base = kb; base < ke; base += 8) {
        int idx = base + part;
        idx = idx < ke - 1 ? idx : ke - 1;       // clamp: always valid load
        int my_s = srcs[idx];
#pragma unroll
        for (int j = 0; j < 8; ++j) {
            int s = __shfl(my_s, g8 * 8 + j, 64);
            float l = a_s[s * 4 + h] + adh;
            l = l > 0.f ? l : NEG_SLOPE * l;
            float e = (base + j < ke) ? __expf(l) : 0.f;
            zacc += e;
            float4 raw = *(const float4*)&xh[(size_t)s * F + part * 8];  // 8 halves
            const __half2* hp = (const __half2*)&raw;
            float2 c0 = __half22float2(hp[0]);
            float2 c1 = __half22float2(hp[1]);
            float2 c2 = __half22float2(hp[2]);
            float2 c3 = __half22float2(hp[3]);
            acc[0] += e * c0.x; acc[1] += e * c0.y;
            acc[2] += e * c1.x; acc[3] += e * c1.y;
            acc[4] += e * c2.x; acc[5] += e * c2.y;
            acc[6] += e * c3.x; acc[7] += e * c3.y;
        }
    }

    float inv = 1.f / zacc;            // zacc > 0 always (self loop)
    float4 bg0 = *(const float4*)&b_gat[part * 8];
    float4 bg1 = *(const float4*)&b_gat[part * 8 + 4];
    float4 o0, o1;
    o0.x = acc[0] * inv + bg0.x; o0.y = acc[1] * inv + bg0.y;
    o0.z = acc[2] * inv + bg0.z; o0.w = acc[3] * inv + bg0.w;
    o1.x = acc[4] * inv + bg1.x; o1.y = acc[5] * inv + bg1.y;
    o1.z = acc[6] * inv + bg1.z; o1.w = acc[7] * inv + bg1.w;
    *(float4*)&h0out[(size_t)n * F + part * 8]     = o0;
    *(float4*)&h0out[(size_t)n * F + part * 8 + 4] = o1;
}

// ---------------------------------------------------------------------------
// MLP + pool. 16 threads per node; activations ping-pong through LDS rows
// (wave-synchronous). h0 input already normalized + biased.
// ---------------------------------------------------------------------------
__global__ void __launch_bounds__(256)
mlp_pool2(const float* __restrict__ h0g,
          const int* __restrict__ batch,
          const float* __restrict__ w_fuse, const float* __restrict__ b_fuse,
          const float* __restrict__ w_h1, const float* __restrict__ b_h1,
          const float* __restrict__ w_h2, const float* __restrict__ b_h2,
          const float* __restrict__ w_h3, const float* __restrict__ b_h3,
          float* __restrict__ sums, float* __restrict__ cnts,
          int n_nodes)
{
    __shared__ __align__(16) float wf[64 * 64];
    __shared__ __align__(16) float w1[64 * 32];
    __shared__ __align__(16) float w2[32 * 16];
    __shared__ __align__(16) float w3[16 * 16];
    __shared__ __align__(16) float bf[64];
    __shared__ __align__(16) float b1[32], b2[16], b3[16];
    __shared__ __align__(16) float actA[16 * AP];
    __shared__ __align__(16) float actB[16 * AP];

    for (int i = threadIdx.x; i < 64 * 64; i += 256) wf[i] = w_fuse[i];
    for (int i = threadIdx.x; i < 64 * 32; i += 256) w1[i] = w_h1[i];
    for (int i = threadIdx.x; i < 32 * 16; i += 256) w2[i] = w_h2[i];
    for (int i = threadIdx.x; i < 16 * 16; i += 256) w3[i] = w_h3[i];
    if (threadIdx.x < 64) bf[threadIdx.x] = b_fuse[threadIdx.x];
    else if (threadIdx.x < 96)  b1[threadIdx.x - 64] = b_h1[threadIdx.x - 64];
    else if (threadIdx.x < 112) b2[threadIdx.x - 96] = b_h2[threadIdx.x - 96];
    else if (threadIdx.x < 128) b3[threadIdx.x - 112] = b_h3[threadIdx.x - 112];

    const int node_l = threadIdx.x >> 4;
    const int part   = threadIdx.x & 15;
    const int n      = blockIdx.x * 16 + node_l;
    const bool active = (n < n_nodes);

    float4 h0 = make_float4(0.f, 0.f, 0.f, 0.f);
    if (active) h0 = *(const float4*)&h0g[(size_t)n * F + part * 4];
    __syncthreads();

    float* rowA = &actA[node_l * AP];
    float* rowB = &actB[node_l * AP];
    *(float4*)&rowA[part * 4] = h0;

    // ---- layer 1: 64 -> 64, relu ----
    {
        float4 a1 = *(const float4*)&bf[part * 4];
#pragma unroll
        for (int k4 = 0; k4 < 16; ++k4) {
            float4 h4 = *(const float4*)&rowA[k4 * 4];
            float4 w0 = *(const float4*)&wf[(k4 * 4 + 0) * 64 + part * 4];
            float4 wq1 = *(const float4*)&wf[(k4 * 4 + 1) * 64 + part * 4];
            float4 wq2 = *(const float4*)&wf[(k4 * 4 + 2) * 64 + part * 4];
            float4 wq3 = *(const float4*)&wf[(k4 * 4 + 3) * 64 + part * 4];
            a1.x += h4.x * w0.x + h4.y * wq1.x + h4.z * wq2.x + h4.w * wq3.x;
            a1.y += h4.x * w0.y + h4.y * wq1.y + h4.z * wq2.y + h4.w * wq3.y;
            a1.z += h4.x * w0.z + h4.y * wq1.z + h4.z * wq2.z + h4.w * wq3.z;
            a1.w += h4.x * w0.w + h4.y * wq1.w + h4.z * wq2.w + h4.w * wq3.w;
        }
        a1.x = a1.x > 0.f ? a1.x : 0.f;
        a1.y = a1.y > 0.f ? a1.y : 0.f;
        a1.z = a1.z > 0.f ? a1.z : 0.f;
        a1.w = a1.w > 0.f ? a1.w : 0.f;
        *(float4*)&rowB[part * 4] = a1;
    }

    // ---- layer 2: 64 -> 32, relu ----
    {
        float ax = b1[part * 2], ay = b1[part * 2 + 1];
#pragma unroll
        for (int k4 = 0; k4 < 16; ++k4) {
            float4 h4 = *(const float4*)&rowB[k4 * 4];
            float2 wa = *(const float2*)&w1[(k4 * 4 + 0) * 32 + part * 2];
            float2 wb = *(const float2*)&w1[(k4 * 4 + 1) * 32 + part * 2];
            float2 wc = *(const float2*)&w1[(k4 * 4 + 2) * 32 + part * 2];
            float2 wd = *(const float2*)&w1[(k4 * 4 + 3) * 32 + part * 2];
            ax += h4.x * wa.x + h4.y * wb.x + h4.z * wc.x + h4.w * wd.x;
            ay += h4.x * wa.y + h4.y * wb.y + h4.z * wc.y + h4.w * wd.y;
        }
        ax = ax > 0.f ? ax : 0.f;
        ay = ay > 0.f ? ay : 0.f;
        float2 uu; uu.x = ax; uu.y = ay;
        *(float2*)&rowA[part * 2] = uu;
    }

    // ---- layer 3: 32 -> 16, relu ----
    {
        float a3 = b2[part];
#pragma unroll
        for (int k4 = 0; k4 < 8; ++k4) {
            float4 h4 = *(const float4*)&rowA[k4 * 4];
            a3 += h4.x * w2[(k4 * 4 + 0) * 16 + part]
                + h4.y * w2[(k4 * 4 + 1) * 16 + part]
                + h4.z * w2[(k4 * 4 + 2) * 16 + part]
                + h4.w * w2[(k4 * 4 + 3) * 16 + part];
        }
        a3 = a3 > 0.f ? a3 : 0.f;
        rowB[part] = a3;
    }

    // ---- layer 4: 16 -> 16, relu ----
    float r;
    {
        float a4 = b3[part];
#pragma unroll
        for (int k4 = 0; k4 < 4; ++k4) {
            float4 h4 = *(const float4*)&rowB[k4 * 4];
            a4 += h4.x * w3[(k4 * 4 + 0) * 16 + part]
                + h4.y * w3[(k4 * 4 + 1) * 16 + part]
                + h4.z * w3[(k4 * 4 + 2) * 16 + part]
                + h4.w * w3[(k4 * 4 + 3) * 16 + part];
        }
        r = a4 > 0.f ? a4 : 0.f;
    }

    if (active) {
        int b = batch[n];
        atomicAdd(&sums[b * 16 + part], r);
        if (part == 0) atomicAdd(&cnts[b], 1.0f);
    }
}

// ---------------------------------------------------------------------------
// g = sums / max(cnt,1); two 16->3 heads.
// ---------------------------------------------------------------------------
__global__ void head_kernel(const float* __restrict__ sums,
                            const float* __restrict__ cnts,
                            const float* __restrict__ w_ev, const float* __restrict__ b_ev,
                            const float* __restrict__ w_env, const float* __restrict__ b_env,
                            float* __restrict__ out, int n_graphs)
{
    int g = blockIdx.x * blockDim.x + threadIdx.x;
    if (g >= n_graphs) return;
    float c = cnts[g];
    c = c > 1.f ? c : 1.f;
    float gg[16];
#pragma unroll
    for (int j = 0; j < 16; ++j) gg[j] = sums[(size_t)g * 16 + j] / c;
#pragma unroll
    for (int j = 0; j < 3; ++j) {
        float a = b_ev[j];
#pragma unroll
        for (int k = 0; k < 16; ++k) a += gg[k] * w_ev[k * 3 + j];
        out[(size_t)g * 3 + j] = a;
    }
#pragma unroll
    for (int j = 0; j < 3; ++j) {
        float a = b_env[j];
#pragma unroll
        for (int k = 0; k < 16; ++k) a += gg[k] * w_env[k * 3 + j];
        out[(size_t)n_graphs * 3 + (size_t)g * 3 + j] = a;
    }
}

// ---------------------------------------------------------------------------
extern "C" void kernel_launch(void* const* d_in, const int* in_sizes, int n_in,
                              void* d_out, int out_size, void* d_ws, size_t ws_size,
                              hipStream_t stream)
{
    const float* x       = (const float*)d_in[0];
    const int*   ei      = (const int*)d_in[1];
    const int*   batch   = (const int*)d_in[2];
    const float* w_gat   = (const float*)d_in[4];
    const float* att_src = (const float*)d_in[5];
    const float* att_dst = (const float*)d_in[6];
    const float* b_gat   = (const float*)d_in[7];
    const float* w_fuse  = (const float*)d_in[8];
    const float* b_fuse  = (const float*)d_in[9];
    const float* w_h1    = (const float*)d_in[10];
    const float* b_h1    = (const float*)d_in[11];
    const float* w_h2    = (const float*)d_in[12];
    const float* b_h2    = (const float*)d_in[13];
    const float* w_h3    = (const float*)d_in[14];
    const float* b_h3    = (const float*)d_in[15];
    const float* w_ev    = (const float*)d_in[16];
    const float* b_ev    = (const float*)d_in[17];
    const float* w_env   = (const float*)d_in[18];
    const float* b_env   = (const float*)d_in[19];

    const int n_nodes  = in_sizes[0] / FIN;       // 100000
    const int E        = in_sizes[1] / 2;         // 3200000
    const int n_graphs = 256;
    const int total    = E + n_nodes;             // edges incl self loops

    // Workspace layout. ~68 MB.
    float* ws     = (float*)d_ws;
    __half* xh    = (__half*)ws;                          // n*64 halves
    float* h0     = ws   + (size_t)n_nodes * 32;          // n*64 fp32
    float* a_s    = h0   + (size_t)n_nodes * F;           // n*4
    float* a_d    = a_s  + (size_t)n_nodes * HEADS;       // n*4
    float* sums   = a_d  + (size_t)n_nodes * HEADS;       // 256*16
    float* cnts   = sums + (size_t)n_graphs * 16;         // 256
    int*   deg    = (int*)(cnts + n_graphs);              // n
    int*   off    = deg    + n_nodes;                     // n+1
    int*   cursor = off    + n_nodes + 1;                 // n
    int*   srcs   = cursor + n_nodes;                     // E+n
    int*   bsums  = srcs   + total;                       // scan block sums (<=128)

    const int nb = (n_nodes + SCAN_CHUNK - 1) / SCAN_CHUNK;   // 98

    hipMemsetAsync(sums, 0, (size_t)(n_graphs * 16 + n_graphs) * sizeof(float), stream);
    hipMemsetAsync(deg, 0, (size_t)n_nodes * sizeof(int), stream);

    node_prep<<<(n_nodes + 255) / 256, 256, 0, stream>>>(
        x, w_gat, att_src, att_dst, xh, a_s, a_d, n_nodes);

    // CSR build (by dst), rebuilt every call (no cross-call state).
    deg_hist<<<(E + 255) / 256, 256, 0, stream>>>(ei, E, deg);
    scan_p1<<<nb, SCAN_BLOCK, 0, stream>>>(deg, bsums, n_nodes);
    scan_p2<<<1, 128, 0, stream>>>(bsums, nb);
    scan_p3<<<nb, SCAN_BLOCK, 0, stream>>>(deg, bsums, off, cursor, n_nodes, total);
    csr_scatter<<<(total + 255) / 256, 256, 0, stream>>>(ei, E, n_nodes, cursor, srcs);

    // Gather: 8 lanes/node -> 32 nodes per 256-thread block.
    gat_gather<<<(n_nodes * 8 + 255) / 256, 256, 0, stream>>>(
        off, srcs, a_s, a_d, xh, b_gat, h0, n_nodes);

    mlp_pool2<<<(n_nodes + 15) / 16, 256, 0, stream>>>(
        h0, batch, w_fuse, b_fuse, w_h1, b_h1, w_h2, b_h2, w_h3, b_h3,
        sums, cnts, n_nodes);

    head_kernel<<<(n_graphs + 255) / 256, 256, 0, stream>>>(
        sums, cnts, w_ev, b_ev, w_env, b_env, (float*)d_out, n_graphs);
}

// Round 7
// 664.265 us; speedup vs baseline: 6.0587x; 1.3971x over previous
//
#include <hip/hip_runtime.h>
#include <hip/hip_bf16.h>
#include <hip/hip_fp16.h>

// N=100000 nodes, F_in=20, 4 heads x 16 ch = 64, E=3.2M edges (+N self loops),
// 256 graphs. All fp32 in/out.
//
// R6: mlp_pool2 was stalled by 1.7M device-scope fp32 atomics into a 17KB
// region (all pipes <7% busy). batch is SORTED -> pool is a segmented
// reduction: mlp writes rfeat[n,16] coalesced, pool_head (1 block/graph,
// binary search for the range) reduces + applies both 16->3 heads. Zero
// float atomics remain anywhere.
#define FIN 20
#define HEADS 4
#define F 64
#define NEG_SLOPE 0.2f
#define SCAN_BLOCK 256
#define SCAN_ITEMS 4
#define SCAN_CHUNK (SCAN_BLOCK * SCAN_ITEMS)   // 1024 elements / block
#define AP 68   // activation row stride (floats)

// ---------------------------------------------------------------------------
// Kernel 1: per-node projection xh(half) = x @ w_gat [N,64] + attn scalars.
// ---------------------------------------------------------------------------
__global__ void node_prep(const float* __restrict__ x,
                          const float* __restrict__ w_gat,
                          const float* __restrict__ att_src,
                          const float* __restrict__ att_dst,
                          __half* __restrict__ xh,
                          float* __restrict__ a_s,
                          float* __restrict__ a_d,
                          int n_nodes)
{
    __shared__ __align__(16) float w[FIN * F];
    __shared__ float asrc[F];
    __shared__ float adst[F];
    for (int i = threadIdx.x; i < FIN * F; i += blockDim.x) w[i] = w_gat[i];
    if (threadIdx.x < F) {
        asrc[threadIdx.x] = att_src[threadIdx.x];
        adst[threadIdx.x] = att_dst[threadIdx.x];
    }
    __syncthreads();

    int n = blockIdx.x * blockDim.x + threadIdx.x;
    if (n >= n_nodes) return;

    float xv[FIN];
#pragma unroll
    for (int q = 0; q < FIN / 4; ++q) {
        float4 x4 = *(const float4*)&x[(size_t)n * FIN + q * 4];
        xv[q * 4 + 0] = x4.x; xv[q * 4 + 1] = x4.y;
        xv[q * 4 + 2] = x4.z; xv[q * 4 + 3] = x4.w;
    }

    float as[HEADS] = {0.f, 0.f, 0.f, 0.f};
    float ad[HEADS] = {0.f, 0.f, 0.f, 0.f};

#pragma unroll
    for (int j4 = 0; j4 < F / 4; ++j4) {
        float4 acc = make_float4(0.f, 0.f, 0.f, 0.f);
#pragma unroll
        for (int k = 0; k < FIN; ++k) {
            float4 w4 = *(const float4*)&w[k * F + j4 * 4];
            acc.x += xv[k] * w4.x;
            acc.y += xv[k] * w4.y;
            acc.z += xv[k] * w4.z;
            acc.w += xv[k] * w4.w;
        }
        __half2 p0 = __floats2half2_rn(acc.x, acc.y);
        __half2 p1 = __floats2half2_rn(acc.z, acc.w);
        float2 st;
        ((__half2*)&st)[0] = p0;
        ((__half2*)&st)[1] = p1;
        *(float2*)&xh[(size_t)n * F + j4 * 4] = st;

        int h = j4 >> 2;
        int jb = j4 * 4;
        as[h] += acc.x * asrc[jb] + acc.y * asrc[jb + 1] + acc.z * asrc[jb + 2] + acc.w * asrc[jb + 3];
        ad[h] += acc.x * adst[jb] + acc.y * adst[jb + 1] + acc.z * adst[jb + 2] + acc.w * adst[jb + 3];
    }
#pragma unroll
    for (int h = 0; h < HEADS; ++h) {
        a_s[(size_t)n * HEADS + h] = as[h];
        a_d[(size_t)n * HEADS + h] = ad[h];
    }
}

// ---------------------------------------------------------------------------
// CSR build: deg = real-edge histogram (deg memset to 0 beforehand).
// ---------------------------------------------------------------------------
__global__ void deg_hist(const int* __restrict__ ei, int E, int* __restrict__ deg)
{
    int e = blockIdx.x * blockDim.x + threadIdx.x;
    if (e >= E) return;
    atomicAdd(&deg[ei[E + e]], 1);
}

// ---------------------------------------------------------------------------
// 3-phase exclusive scan of deg. Self-loops folded in: off[i]=scan(deg)[i]+i.
// ---------------------------------------------------------------------------
__global__ void scan_p1(const int* __restrict__ deg, int* __restrict__ bsums, int n)
{
    __shared__ int sh[SCAN_BLOCK];
    int base = blockIdx.x * SCAN_CHUNK + threadIdx.x * SCAN_ITEMS;
    int s = 0;
    if (base + SCAN_ITEMS <= n) {
        int4 v = *(const int4*)&deg[base];
        s = v.x + v.y + v.z + v.w;
    } else {
        for (int j = 0; j < SCAN_ITEMS; ++j) { int i = base + j; if (i < n) s += deg[i]; }
    }
    sh[threadIdx.x] = s;
    __syncthreads();
    for (int d = SCAN_BLOCK / 2; d > 0; d >>= 1) {
        if (threadIdx.x < d) sh[threadIdx.x] += sh[threadIdx.x + d];
        __syncthreads();
    }
    if (threadIdx.x == 0) bsums[blockIdx.x] = sh[0];
}

__global__ void scan_p2(int* __restrict__ bsums, int nb)
{
    __shared__ int sh[128];
    int t = threadIdx.x;
    int v = (t < nb) ? bsums[t] : 0;
    sh[t] = v;
    __syncthreads();
    for (int d = 1; d < 128; d <<= 1) {
        int w = (t >= d) ? sh[t - d] : 0;
        __syncthreads();
        sh[t] += w;
        __syncthreads();
    }
    if (t < nb) bsums[t] = (t == 0) ? 0 : sh[t - 1];   // exclusive
}

__global__ void scan_p3(const int* __restrict__ deg, const int* __restrict__ bpre,
                        int* __restrict__ off, int* __restrict__ cursor,
                        int n, int total)
{
    __shared__ int sh[SCAN_BLOCK];
    int t = threadIdx.x;
    int base = blockIdx.x * SCAN_CHUNK + t * SCAN_ITEMS;
    int v[SCAN_ITEMS];
    int s = 0;
    if (base + SCAN_ITEMS <= n) {
        int4 q = *(const int4*)&deg[base];
        v[0] = q.x; v[1] = q.y; v[2] = q.z; v[3] = q.w;
        s = q.x + q.y + q.z + q.w;
    } else {
#pragma unroll
        for (int j = 0; j < SCAN_ITEMS; ++j) { int i = base + j; v[j] = (i < n) ? deg[i] : 0; s += v[j]; }
    }
    sh[t] = s;
    __syncthreads();
    for (int d = 1; d < SCAN_BLOCK; d <<= 1) {
        int w = (t >= d) ? sh[t - d] : 0;
        __syncthreads();
        sh[t] += w;
        __syncthreads();
    }
    int run = bpre[blockIdx.x] + ((t == 0) ? 0 : sh[t - 1]);
#pragma unroll
    for (int j = 0; j < SCAN_ITEMS; ++j) {
        int i = base + j;
        if (i < n) {
            int o = run + i;        // +i accounts for one self-loop per node
            off[i] = o;
            cursor[i] = o;
            run += v[j];
        }
    }
    if (blockIdx.x == 0 && t == 0) off[n] = total;
}

// ---------------------------------------------------------------------------
// CSR scatter: src ids into dst buckets. e in [E,E+N) = self loop.
// ---------------------------------------------------------------------------
__global__ void csr_scatter(const int* __restrict__ ei, int E, int n_nodes,
                            int* __restrict__ cursor, int* __restrict__ srcs)
{
    int e = blockIdx.x * blockDim.x + threadIdx.x;
    int total = E + n_nodes;
    if (e >= total) return;
    int src, dst;
    if (e < E) { src = ei[e]; dst = ei[E + e]; }
    else       { src = dst = e - E; }
    int p = atomicAdd(&cursor[dst], 1);
    srcs[p] = src;
}

// ---------------------------------------------------------------------------
// Gather: 8 lanes per node, branch-free clamped 8-edge chunks, no LDS.
// Writes h0 = acc/z + b_gat.
// ---------------------------------------------------------------------------
__global__ void __launch_bounds__(256)
gat_gather(const int* __restrict__ off,
           const int* __restrict__ srcs,
           const float* __restrict__ a_s,
           const float* __restrict__ a_d,
           const __half* __restrict__ xh,
           const float* __restrict__ b_gat,
           float* __restrict__ h0out,
           int n_nodes)
{
    int tid = blockIdx.x * 256 + threadIdx.x;
    int n = tid >> 3;
    int part = tid & 7;
    if (n >= n_nodes) return;
    const int h = part >> 1;
    const int g8 = (threadIdx.x & 63) >> 3;   // node slot within wave (0..7)

    int kb = off[n];
    int ke = off[n + 1];
    float adh = a_d[n * 4 + h];

    float acc[8] = {0.f, 0.f, 0.f, 0.f, 0.f, 0.f, 0.f, 0.f};
    float zacc = 0.f;

    for (int base = kb; base < ke; base += 8) {
        int idx = base + part;
        idx = idx < ke - 1 ? idx : ke - 1;       // clamp: always valid load
        int my_s = srcs[idx];
#pragma unroll
        for (int j = 0; j < 8; ++j) {
            int s = __shfl(my_s, g8 * 8 + j, 64);
            float l = a_s[s * 4 + h] + adh;
            l = l > 0.f ? l : NEG_SLOPE * l;
            float e = (base + j < ke) ? __expf(l) : 0.f;
            zacc += e;
            float4 raw = *(const float4*)&xh[(size_t)s * F + part * 8];  // 8 halves
            const __half2* hp = (const __half2*)&raw;
            float2 c0 = __half22float2(hp[0]);
            float2 c1 = __half22float2(hp[1]);
            float2 c2 = __half22float2(hp[2]);
            float2 c3 = __half22float2(hp[3]);
            acc[0] += e * c0.x; acc[1] += e * c0.y;
            acc[2] += e * c1.x; acc[3] += e * c1.y;
            acc[4] += e * c2.x; acc[5] += e * c2.y;
            acc[6] += e * c3.x; acc[7] += e * c3.y;
        }
    }

    float inv = 1.f / zacc;            // zacc > 0 always (self loop)
    float4 bg0 = *(const float4*)&b_gat[part * 8];
    float4 bg1 = *(const float4*)&b_gat[part * 8 + 4];
    float4 o0, o1;
    o0.x = acc[0] * inv + bg0.x; o0.y = acc[1] * inv + bg0.y;
    o0.z = acc[2] * inv + bg0.z; o0.w = acc[3] * inv + bg0.w;
    o1.x = acc[4] * inv + bg1.x; o1.y = acc[5] * inv + bg1.y;
    o1.z = acc[6] * inv + bg1.z; o1.w = acc[7] * inv + bg1.w;
    *(float4*)&h0out[(size_t)n * F + part * 8]     = o0;
    *(float4*)&h0out[(size_t)n * F + part * 8 + 4] = o1;
}

// ---------------------------------------------------------------------------
// MLP. 16 threads per node; LDS ping-pong activations (wave-synchronous).
// Output: rfeat[n,16] coalesced plain stores (addr = blockIdx*256 + tid).
// ---------------------------------------------------------------------------
__global__ void __launch_bounds__(256)
mlp_pool2(const float* __restrict__ h0g,
          const float* __restrict__ w_fuse, const float* __restrict__ b_fuse,
          const float* __restrict__ w_h1, const float* __restrict__ b_h1,
          const float* __restrict__ w_h2, const float* __restrict__ b_h2,
          const float* __restrict__ w_h3, const float* __restrict__ b_h3,
          float* __restrict__ rfeat,
          int n_nodes)
{
    __shared__ __align__(16) float wf[64 * 64];
    __shared__ __align__(16) float w1[64 * 32];
    __shared__ __align__(16) float w2[32 * 16];
    __shared__ __align__(16) float w3[16 * 16];
    __shared__ __align__(16) float bf[64];
    __shared__ __align__(16) float b1[32], b2[16], b3[16];
    __shared__ __align__(16) float actA[16 * AP];
    __shared__ __align__(16) float actB[16 * AP];

    for (int i = threadIdx.x; i < 64 * 64; i += 256) wf[i] = w_fuse[i];
    for (int i = threadIdx.x; i < 64 * 32; i += 256) w1[i] = w_h1[i];
    for (int i = threadIdx.x; i < 32 * 16; i += 256) w2[i] = w_h2[i];
    for (int i = threadIdx.x; i < 16 * 16; i += 256) w3[i] = w_h3[i];
    if (threadIdx.x < 64) bf[threadIdx.x] = b_fuse[threadIdx.x];
    else if (threadIdx.x < 96)  b1[threadIdx.x - 64] = b_h1[threadIdx.x - 64];
    else if (threadIdx.x < 112) b2[threadIdx.x - 96] = b_h2[threadIdx.x - 96];
    else if (threadIdx.x < 128) b3[threadIdx.x - 112] = b_h3[threadIdx.x - 112];

    const int node_l = threadIdx.x >> 4;
    const int part   = threadIdx.x & 15;
    const int n      = blockIdx.x * 16 + node_l;
    const bool active = (n < n_nodes);

    float4 h0 = make_float4(0.f, 0.f, 0.f, 0.f);
    if (active) h0 = *(const float4*)&h0g[(size_t)n * F + part * 4];
    __syncthreads();

    float* rowA = &actA[node_l * AP];
    float* rowB = &actB[node_l * AP];
    *(float4*)&rowA[part * 4] = h0;

    // ---- layer 1: 64 -> 64, relu ----
    {
        float4 a1 = *(const float4*)&bf[part * 4];
#pragma unroll
        for (int k4 = 0; k4 < 16; ++k4) {
            float4 h4 = *(const float4*)&rowA[k4 * 4];
            float4 w0 = *(const float4*)&wf[(k4 * 4 + 0) * 64 + part * 4];
            float4 wq1 = *(const float4*)&wf[(k4 * 4 + 1) * 64 + part * 4];
            float4 wq2 = *(const float4*)&wf[(k4 * 4 + 2) * 64 + part * 4];
            float4 wq3 = *(const float4*)&wf[(k4 * 4 + 3) * 64 + part * 4];
            a1.x += h4.x * w0.x + h4.y * wq1.x + h4.z * wq2.x + h4.w * wq3.x;
            a1.y += h4.x * w0.y + h4.y * wq1.y + h4.z * wq2.y + h4.w * wq3.y;
            a1.z += h4.x * w0.z + h4.y * wq1.z + h4.z * wq2.z + h4.w * wq3.z;
            a1.w += h4.x * w0.w + h4.y * wq1.w + h4.z * wq2.w + h4.w * wq3.w;
        }
        a1.x = a1.x > 0.f ? a1.x : 0.f;
        a1.y = a1.y > 0.f ? a1.y : 0.f;
        a1.z = a1.z > 0.f ? a1.z : 0.f;
        a1.w = a1.w > 0.f ? a1.w : 0.f;
        *(float4*)&rowB[part * 4] = a1;
    }

    // ---- layer 2: 64 -> 32, relu ----
    {
        float ax = b1[part * 2], ay = b1[part * 2 + 1];
#pragma unroll
        for (int k4 = 0; k4 < 16; ++k4) {
            float4 h4 = *(const float4*)&rowB[k4 * 4];
            float2 wa = *(const float2*)&w1[(k4 * 4 + 0) * 32 + part * 2];
            float2 wb = *(const float2*)&w1[(k4 * 4 + 1) * 32 + part * 2];
            float2 wc = *(const float2*)&w1[(k4 * 4 + 2) * 32 + part * 2];
            float2 wd = *(const float2*)&w1[(k4 * 4 + 3) * 32 + part * 2];
            ax += h4.x * wa.x + h4.y * wb.x + h4.z * wc.x + h4.w * wd.x;
            ay += h4.x * wa.y + h4.y * wb.y + h4.z * wc.y + h4.w * wd.y;
        }
        ax = ax > 0.f ? ax : 0.f;
        ay = ay > 0.f ? ay : 0.f;
        float2 uu; uu.x = ax; uu.y = ay;
        *(float2*)&rowA[part * 2] = uu;
    }

    // ---- layer 3: 32 -> 16, relu ----
    {
        float a3 = b2[part];
#pragma unroll
        for (int k4 = 0; k4 < 8; ++k4) {
            float4 h4 = *(const float4*)&rowA[k4 * 4];
            a3 += h4.x * w2[(k4 * 4 + 0) * 16 + part]
                + h4.y * w2[(k4 * 4 + 1) * 16 + part]
                + h4.z * w2[(k4 * 4 + 2) * 16 + part]
                + h4.w * w2[(k4 * 4 + 3) * 16 + part];
        }
        a3 = a3 > 0.f ? a3 : 0.f;
        rowB[part] = a3;
    }

    // ---- layer 4: 16 -> 16, relu ----
    float r;
    {
        float a4 = b3[part];
#pragma unroll
        for (int k4 = 0; k4 < 4; ++k4) {
            float4 h4 = *(const float4*)&rowB[k4 * 4];
            a4 += h4.x * w3[(k4 * 4 + 0) * 16 + part]
                + h4.y * w3[(k4 * 4 + 1) * 16 + part]
                + h4.z * w3[(k4 * 4 + 2) * 16 + part]
                + h4.w * w3[(k4 * 4 + 3) * 16 + part];
        }
        r = a4 > 0.f ? a4 : 0.f;
    }

    if (active) rfeat[(size_t)n * 16 + part] = r;   // fully coalesced
}

// ---------------------------------------------------------------------------
// Segmented mean-pool + both heads. One block per graph; batch is sorted, so
// the graph's nodes are [start,end) found by binary search. 16 channel x 16
// node-stream register accumulation, LDS reduce, then the two 16->3 heads.
// ---------------------------------------------------------------------------
__global__ void __launch_bounds__(256)
pool_head(const float* __restrict__ rfeat, const int* __restrict__ batch,
          const float* __restrict__ w_ev, const float* __restrict__ b_ev,
          const float* __restrict__ w_env, const float* __restrict__ b_env,
          float* __restrict__ out, int n_nodes, int n_graphs)
{
    __shared__ int s_bounds[2];
    __shared__ float partial[16][17];
    __shared__ float gvec[16];

    int g = blockIdx.x;
    if (threadIdx.x < 2) {
        int target = g + threadIdx.x;          // lower_bound(batch, target)
        int lo = 0, hi = n_nodes;
        while (lo < hi) { int m = (lo + hi) >> 1; if (batch[m] < target) lo = m + 1; else hi = m; }
        s_bounds[threadIdx.x] = lo;
    }
    __syncthreads();
    int start = s_bounds[0], end = s_bounds[1];

    const int c = threadIdx.x & 15;     // channel
    const int w = threadIdx.x >> 4;     // node stream
    float acc = 0.f;
    for (int i = start + w; i < end; i += 16)
        acc += rfeat[(size_t)i * 16 + c];
    partial[w][c] = acc;
    __syncthreads();

    if (threadIdx.x < 16) {
        float s = 0.f;
#pragma unroll
        for (int ww = 0; ww < 16; ++ww) s += partial[ww][threadIdx.x];
        float cnt = (float)(end - start);
        cnt = cnt > 1.f ? cnt : 1.f;
        gvec[threadIdx.x] = s / cnt;
    }
    __syncthreads();

    if (threadIdx.x < 3) {
        int j = threadIdx.x;
        float a = b_ev[j];
#pragma unroll
        for (int k = 0; k < 16; ++k) a += gvec[k] * w_ev[k * 3 + j];
        out[(size_t)g * 3 + j] = a;
    } else if (threadIdx.x < 6) {
        int j = threadIdx.x - 3;
        float a = b_env[j];
#pragma unroll
        for (int k = 0; k < 16; ++k) a += gvec[k] * w_env[k * 3 + j];
        out[(size_t)n_graphs * 3 + (size_t)g * 3 + j] = a;
    }
}

// ---------------------------------------------------------------------------
extern "C" void kernel_launch(void* const* d_in, const int* in_sizes, int n_in,
                              void* d_out, int out_size, void* d_ws, size_t ws_size,
                              hipStream_t stream)
{
    const float* x       = (const float*)d_in[0];
    const int*   ei      = (const int*)d_in[1];
    const int*   batch   = (const int*)d_in[2];
    const float* w_gat   = (const float*)d_in[4];
    const float* att_src = (const float*)d_in[5];
    const float* att_dst = (const float*)d_in[6];
    const float* b_gat   = (const float*)d_in[7];
    const float* w_fuse  = (const float*)d_in[8];
    const float* b_fuse  = (const float*)d_in[9];
    const float* w_h1    = (const float*)d_in[10];
    const float* b_h1    = (const float*)d_in[11];
    const float* w_h2    = (const float*)d_in[12];
    const float* b_h2    = (const float*)d_in[13];
    const float* w_h3    = (const float*)d_in[14];
    const float* b_h3    = (const float*)d_in[15];
    const float* w_ev    = (const float*)d_in[16];
    const float* b_ev    = (const float*)d_in[17];
    const float* w_env   = (const float*)d_in[18];
    const float* b_env   = (const float*)d_in[19];

    const int n_nodes  = in_sizes[0] / FIN;       // 100000
    const int E        = in_sizes[1] / 2;         // 3200000
    const int n_graphs = 256;
    const int total    = E + n_nodes;             // edges incl self loops

    // Workspace layout. ~68 MB.
    float* ws     = (float*)d_ws;
    __half* xh    = (__half*)ws;                          // n*64 halves
    float* h0     = ws   + (size_t)n_nodes * 32;          // n*64 fp32
    float* a_s    = h0   + (size_t)n_nodes * F;           // n*4
    float* a_d    = a_s  + (size_t)n_nodes * HEADS;       // n*4
    float* rfeat  = a_d  + (size_t)n_nodes * HEADS;       // n*16
    int*   deg    = (int*)(rfeat + (size_t)n_nodes * 16); // n
    int*   off    = deg    + n_nodes;                     // n+1
    int*   cursor = off    + n_nodes + 1;                 // n
    int*   srcs   = cursor + n_nodes;                     // E+n
    int*   bsums  = srcs   + total;                       // scan block sums (<=128)

    const int nb = (n_nodes + SCAN_CHUNK - 1) / SCAN_CHUNK;   // 98

    hipMemsetAsync(deg, 0, (size_t)n_nodes * sizeof(int), stream);

    node_prep<<<(n_nodes + 255) / 256, 256, 0, stream>>>(
        x, w_gat, att_src, att_dst, xh, a_s, a_d, n_nodes);

    // CSR build (by dst), rebuilt every call (no cross-call state).
    deg_hist<<<(E + 255) / 256, 256, 0, stream>>>(ei, E, deg);
    scan_p1<<<nb, SCAN_BLOCK, 0, stream>>>(deg, bsums, n_nodes);
    scan_p2<<<1, 128, 0, stream>>>(bsums, nb);
    scan_p3<<<nb, SCAN_BLOCK, 0, stream>>>(deg, bsums, off, cursor, n_nodes, total);
    csr_scatter<<<(total + 255) / 256, 256, 0, stream>>>(ei, E, n_nodes, cursor, srcs);

    // Gather: 8 lanes/node -> 32 nodes per 256-thread block.
    gat_gather<<<(n_nodes * 8 + 255) / 256, 256, 0, stream>>>(
        off, srcs, a_s, a_d, xh, b_gat, h0, n_nodes);

    mlp_pool2<<<(n_nodes + 15) / 16, 256, 0, stream>>>(
        h0, w_fuse, b_fuse, w_h1, b_h1, w_h2, b_h2, w_h3, b_h3,
        rfeat, n_nodes);

    pool_head<<<n_graphs, 256, 0, stream>>>(
        rfeat, batch, w_ev, b_ev, w_env, b_env, (float*)d_out, n_nodes, n_graphs);
}

// Round 8
// 347.539 us; speedup vs baseline: 11.5803x; 1.9113x over previous
//
#include <hip/hip_runtime.h>
#include <hip/hip_bf16.h>
#include <hip/hip_fp16.h>

// N=100000 nodes, F_in=20, 4 heads x 16 ch = 64, E=3.2M edges (+N self loops),
// 256 graphs. All fp32 in/out.
//
// R7: csr_scatter wrote 197MB for a 13MB payload (3.3M random 4B stores = one
// 64B line each) at 0.4% VALU; deg_hist similar. Replaced the whole CSR build
// with a two-level bucket sort: bin_pass (LDS-staged binning into 196 buckets
// of 512 dst nodes, ~21-edge contiguous runs per bucket per block, 153K global
// atomics), bucket_scan (196-entry scan), csr_build (per-bucket LDS hist+scan,
// scatter confined to ~70KB L2-resident window). bucketData overlays h0.
#define FIN 20
#define HEADS 4
#define F 64
#define NEG_SLOPE 0.2f
#define AP 68        // activation row stride (floats)
#define BSHIFT 9     // 512 nodes per bucket
#define BMASK 511
#define BCAP 18432   // per-bucket edge capacity (mean 16384, +16 sigma)
#define MAXBUCK 256
#define BIN_EPT 16   // edges per thread in bin_pass

// ---------------------------------------------------------------------------
// Kernel 1: per-node projection xh(half) = x @ w_gat [N,64] + attn scalars.
// ---------------------------------------------------------------------------
__global__ void node_prep(const float* __restrict__ x,
                          const float* __restrict__ w_gat,
                          const float* __restrict__ att_src,
                          const float* __restrict__ att_dst,
                          __half* __restrict__ xh,
                          float* __restrict__ a_s,
                          float* __restrict__ a_d,
                          int n_nodes)
{
    __shared__ __align__(16) float w[FIN * F];
    __shared__ float asrc[F];
    __shared__ float adst[F];
    for (int i = threadIdx.x; i < FIN * F; i += blockDim.x) w[i] = w_gat[i];
    if (threadIdx.x < F) {
        asrc[threadIdx.x] = att_src[threadIdx.x];
        adst[threadIdx.x] = att_dst[threadIdx.x];
    }
    __syncthreads();

    int n = blockIdx.x * blockDim.x + threadIdx.x;
    if (n >= n_nodes) return;

    float xv[FIN];
#pragma unroll
    for (int q = 0; q < FIN / 4; ++q) {
        float4 x4 = *(const float4*)&x[(size_t)n * FIN + q * 4];
        xv[q * 4 + 0] = x4.x; xv[q * 4 + 1] = x4.y;
        xv[q * 4 + 2] = x4.z; xv[q * 4 + 3] = x4.w;
    }

    float as[HEADS] = {0.f, 0.f, 0.f, 0.f};
    float ad[HEADS] = {0.f, 0.f, 0.f, 0.f};

#pragma unroll
    for (int j4 = 0; j4 < F / 4; ++j4) {
        float4 acc = make_float4(0.f, 0.f, 0.f, 0.f);
#pragma unroll
        for (int k = 0; k < FIN; ++k) {
            float4 w4 = *(const float4*)&w[k * F + j4 * 4];
            acc.x += xv[k] * w4.x;
            acc.y += xv[k] * w4.y;
            acc.z += xv[k] * w4.z;
            acc.w += xv[k] * w4.w;
        }
        __half2 p0 = __floats2half2_rn(acc.x, acc.y);
        __half2 p1 = __floats2half2_rn(acc.z, acc.w);
        float2 st;
        ((__half2*)&st)[0] = p0;
        ((__half2*)&st)[1] = p1;
        *(float2*)&xh[(size_t)n * F + j4 * 4] = st;

        int h = j4 >> 2;
        int jb = j4 * 4;
        as[h] += acc.x * asrc[jb] + acc.y * asrc[jb + 1] + acc.z * asrc[jb + 2] + acc.w * asrc[jb + 3];
        ad[h] += acc.x * adst[jb] + acc.y * adst[jb + 1] + acc.z * adst[jb + 2] + acc.w * adst[jb + 3];
    }
#pragma unroll
    for (int h = 0; h < HEADS; ++h) {
        a_s[(size_t)n * HEADS + h] = as[h];
        a_d[(size_t)n * HEADS + h] = ad[h];
    }
}

// ---------------------------------------------------------------------------
// CSR build pass A: bin edges by dst bucket (512 nodes/bucket). LDS-staged:
// per-block bucket counts -> one global reservation atomic per bucket ->
// packed (dstlocal<<17 | src) words written in contiguous runs per bucket.
// ---------------------------------------------------------------------------
__global__ void __launch_bounds__(256)
bin_pass(const int* __restrict__ ei, int E, int nbuck,
         int* __restrict__ gcount, int* __restrict__ bucketData)
{
    __shared__ int lcnt[MAXBUCK];
    __shared__ int lbase[MAXBUCK];
    for (int i = threadIdx.x; i < nbuck; i += 256) lcnt[i] = 0;
    __syncthreads();

    int base = blockIdx.x * (256 * BIN_EPT);
    int b_[BIN_EPT], w_[BIN_EPT];
#pragma unroll
    for (int j = 0; j < BIN_EPT; ++j) {
        int e = base + j * 256 + threadIdx.x;
        if (e < E) {
            int src = ei[e];
            int dst = ei[E + e];
            b_[j] = dst >> BSHIFT;
            w_[j] = ((dst & BMASK) << 17) | src;   // src < 2^17 (N=100000)
            atomicAdd(&lcnt[b_[j]], 1);
        } else b_[j] = -1;
    }
    __syncthreads();
    for (int i = threadIdx.x; i < nbuck; i += 256) {
        int c = lcnt[i];
        lbase[i] = c ? atomicAdd(&gcount[i], c) : 0;
        lcnt[i] = 0;
    }
    __syncthreads();
#pragma unroll
    for (int j = 0; j < BIN_EPT; ++j) {
        if (b_[j] >= 0) {
            int p = lbase[b_[j]] + atomicAdd(&lcnt[b_[j]], 1);
            if (p < BCAP) bucketData[(size_t)b_[j] * BCAP + p] = w_[j];
        }
    }
}

// ---------------------------------------------------------------------------
// CSR build pass B1: exclusive scan of bucket totals; self loops folded in
// (bbase[b] += b*512: all earlier buckets are full). Writes off[n] terminator.
// ---------------------------------------------------------------------------
__global__ void __launch_bounds__(256)
bucket_scan(const int* __restrict__ gcount, int* __restrict__ bbase,
            int* __restrict__ off, int nbuck, int n_nodes, int E)
{
    __shared__ int sh[MAXBUCK];
    int t = threadIdx.x;
    int v = (t < nbuck) ? gcount[t] : 0;
    sh[t] = v;
    __syncthreads();
    for (int d = 1; d < MAXBUCK; d <<= 1) {
        int w = (t >= d) ? sh[t - d] : 0;
        __syncthreads();
        sh[t] += w;
        __syncthreads();
    }
    if (t < nbuck) bbase[t] = sh[t] - v + (t << BSHIFT);
    if (t == 0) off[n_nodes] = E + n_nodes;
}

// ---------------------------------------------------------------------------
// CSR build pass B2: one block per bucket. LDS histogram of the bucket's
// <=512 nodes, local scan (+1/node for the self loop, planted first), write
// off[] coalesced, then scatter real edges within the bucket's ~70KB
// L2-resident CSR window.
// ---------------------------------------------------------------------------
__global__ void __launch_bounds__(256)
csr_build(const int* __restrict__ bucketData, const int* __restrict__ gcount,
          const int* __restrict__ bbase, int* __restrict__ off,
          int* __restrict__ srcs, int n_nodes)
{
    __shared__ int hist[512];     // reused as per-node cursor after the scan
    __shared__ int psum[256];
    int b = blockIdx.x;
    int t = threadIdx.x;
    int cnt = gcount[b]; if (cnt > BCAP) cnt = BCAP;
    int node0 = b << BSHIFT;
    int nnode = n_nodes - node0; if (nnode > 512) nnode = 512;

    hist[t] = 0; hist[t + 256] = 0;
    __syncthreads();
    const int* bd = bucketData + (size_t)b * BCAP;
    for (int i = t; i < cnt; i += 256) atomicAdd(&hist[bd[i] >> 17], 1);
    __syncthreads();

    int i0 = 2 * t, i1 = 2 * t + 1;
    int v0 = (i0 < nnode) ? hist[i0] + 1 : 0;   // +1: self loop slot
    int v1 = (i1 < nnode) ? hist[i1] + 1 : 0;
    psum[t] = v0 + v1;
    __syncthreads();
    for (int d = 1; d < 256; d <<= 1) {
        int w = (t >= d) ? psum[t - d] : 0;
        __syncthreads();
        psum[t] += w;
        __syncthreads();
    }
    int ex = (t == 0) ? 0 : psum[t - 1];
    int base = bbase[b];
    __syncthreads();                 // hist reads done; reuse as cursor
    if (i0 < nnode) {
        int o = base + ex;
        off[node0 + i0] = o;
        srcs[o] = node0 + i0;        // self loop first
        hist[i0] = o + 1;
    }
    if (i1 < nnode) {
        int o = base + ex + v0;
        off[node0 + i1] = o;
        srcs[o] = node0 + i1;
        hist[i1] = o + 1;
    }
    __syncthreads();
    for (int i = t; i < cnt; i += 256) {
        int w = bd[i];
        int p = atomicAdd(&hist[w >> 17], 1);
        srcs[p] = w & 0x1FFFF;
    }
}

// ---------------------------------------------------------------------------
// Gather: 8 lanes per node, branch-free clamped 8-edge chunks, no LDS.
// Writes h0 = acc/z + b_gat.
// ---------------------------------------------------------------------------
__global__ void __launch_bounds__(256)
gat_gather(const int* __restrict__ off,
           const int* __restrict__ srcs,
           const float* __restrict__ a_s,
           const float* __restrict__ a_d,
           const __half* __restrict__ xh,
           const float* __restrict__ b_gat,
           float* __restrict__ h0out,
           int n_nodes)
{
    int tid = blockIdx.x * 256 + threadIdx.x;
    int n = tid >> 3;
    int part = tid & 7;
    if (n >= n_nodes) return;
    const int h = part >> 1;
    const int g8 = (threadIdx.x & 63) >> 3;   // node slot within wave (0..7)

    int kb = off[n];
    int ke = off[n + 1];
    float adh = a_d[n * 4 + h];

    float acc[8] = {0.f, 0.f, 0.f, 0.f, 0.f, 0.f, 0.f, 0.f};
    float zacc = 0.f;

    for (int base = kb; base < ke; base += 8) {
        int idx = base + part;
        idx = idx < ke - 1 ? idx : ke - 1;       // clamp: always valid load
        int my_s = srcs[idx];
#pragma unroll
        for (int j = 0; j < 8; ++j) {
            int s = __shfl(my_s, g8 * 8 + j, 64);
            float l = a_s[s * 4 + h] + adh;
            l = l > 0.f ? l : NEG_SLOPE * l;
            float e = (base + j < ke) ? __expf(l) : 0.f;
            zacc += e;
            float4 raw = *(const float4*)&xh[(size_t)s * F + part * 8];  // 8 halves
            const __half2* hp = (const __half2*)&raw;
            float2 c0 = __half22float2(hp[0]);
            float2 c1 = __half22float2(hp[1]);
            float2 c2 = __half22float2(hp[2]);
            float2 c3 = __half22float2(hp[3]);
            acc[0] += e * c0.x; acc[1] += e * c0.y;
            acc[2] += e * c1.x; acc[3] += e * c1.y;
            acc[4] += e * c2.x; acc[5] += e * c2.y;
            acc[6] += e * c3.x; acc[7] += e * c3.y;
        }
    }

    float inv = 1.f / zacc;            // zacc > 0 always (self loop)
    float4 bg0 = *(const float4*)&b_gat[part * 8];
    float4 bg1 = *(const float4*)&b_gat[part * 8 + 4];
    float4 o0, o1;
    o0.x = acc[0] * inv + bg0.x; o0.y = acc[1] * inv + bg0.y;
    o0.z = acc[2] * inv + bg0.z; o0.w = acc[3] * inv + bg0.w;
    o1.x = acc[4] * inv + bg1.x; o1.y = acc[5] * inv + bg1.y;
    o1.z = acc[6] * inv + bg1.z; o1.w = acc[7] * inv + bg1.w;
    *(float4*)&h0out[(size_t)n * F + part * 8]     = o0;
    *(float4*)&h0out[(size_t)n * F + part * 8 + 4] = o1;
}

// ---------------------------------------------------------------------------
// MLP. 16 threads per node; LDS ping-pong activations (wave-synchronous).
// Output: rfeat[n,16] coalesced plain stores.
// ---------------------------------------------------------------------------
__global__ void __launch_bounds__(256)
mlp_pool2(const float* __restrict__ h0g,
          const float* __restrict__ w_fuse, const float* __restrict__ b_fuse,
          const float* __restrict__ w_h1, const float* __restrict__ b_h1,
          const float* __restrict__ w_h2, const float* __restrict__ b_h2,
          const float* __restrict__ w_h3, const float* __restrict__ b_h3,
          float* __restrict__ rfeat,
          int n_nodes)
{
    __shared__ __align__(16) float wf[64 * 64];
    __shared__ __align__(16) float w1[64 * 32];
    __shared__ __align__(16) float w2[32 * 16];
    __shared__ __align__(16) float w3[16 * 16];
    __shared__ __align__(16) float bf[64];
    __shared__ __align__(16) float b1[32], b2[16], b3[16];
    __shared__ __align__(16) float actA[16 * AP];
    __shared__ __align__(16) float actB[16 * AP];

    for (int i = threadIdx.x; i < 64 * 64; i += 256) wf[i] = w_fuse[i];
    for (int i = threadIdx.x; i < 64 * 32; i += 256) w1[i] = w_h1[i];
    for (int i = threadIdx.x; i < 32 * 16; i += 256) w2[i] = w_h2[i];
    for (int i = threadIdx.x; i < 16 * 16; i += 256) w3[i] = w_h3[i];
    if (threadIdx.x < 64) bf[threadIdx.x] = b_fuse[threadIdx.x];
    else if (threadIdx.x < 96)  b1[threadIdx.x - 64] = b_h1[threadIdx.x - 64];
    else if (threadIdx.x < 112) b2[threadIdx.x - 96] = b_h2[threadIdx.x - 96];
    else if (threadIdx.x < 128) b3[threadIdx.x - 112] = b_h3[threadIdx.x - 112];

    const int node_l = threadIdx.x >> 4;
    const int part   = threadIdx.x & 15;
    const int n      = blockIdx.x * 16 + node_l;
    const bool active = (n < n_nodes);

    float4 h0 = make_float4(0.f, 0.f, 0.f, 0.f);
    if (active) h0 = *(const float4*)&h0g[(size_t)n * F + part * 4];
    __syncthreads();

    float* rowA = &actA[node_l * AP];
    float* rowB = &actB[node_l * AP];
    *(float4*)&rowA[part * 4] = h0;

    // ---- layer 1: 64 -> 64, relu ----
    {
        float4 a1 = *(const float4*)&bf[part * 4];
#pragma unroll
        for (int k4 = 0; k4 < 16; ++k4) {
            float4 h4 = *(const float4*)&rowA[k4 * 4];
            float4 w0 = *(const float4*)&wf[(k4 * 4 + 0) * 64 + part * 4];
            float4 wq1 = *(const float4*)&wf[(k4 * 4 + 1) * 64 + part * 4];
            float4 wq2 = *(const float4*)&wf[(k4 * 4 + 2) * 64 + part * 4];
            float4 wq3 = *(const float4*)&wf[(k4 * 4 + 3) * 64 + part * 4];
            a1.x += h4.x * w0.x + h4.y * wq1.x + h4.z * wq2.x + h4.w * wq3.x;
            a1.y += h4.x * w0.y + h4.y * wq1.y + h4.z * wq2.y + h4.w * wq3.y;
            a1.z += h4.x * w0.z + h4.y * wq1.z + h4.z * wq2.z + h4.w * wq3.z;
            a1.w += h4.x * w0.w + h4.y * wq1.w + h4.z * wq2.w + h4.w * wq3.w;
        }
        a1.x = a1.x > 0.f ? a1.x : 0.f;
        a1.y = a1.y > 0.f ? a1.y : 0.f;
        a1.z = a1.z > 0.f ? a1.z : 0.f;
        a1.w = a1.w > 0.f ? a1.w : 0.f;
        *(float4*)&rowB[part * 4] = a1;
    }

    // ---- layer 2: 64 -> 32, relu ----
    {
        float ax = b1[part * 2], ay = b1[part * 2 + 1];
#pragma unroll
        for (int k4 = 0; k4 < 16; ++k4) {
            float4 h4 = *(const float4*)&rowB[k4 * 4];
            float2 wa = *(const float2*)&w1[(k4 * 4 + 0) * 32 + part * 2];
            float2 wb = *(const float2*)&w1[(k4 * 4 + 1) * 32 + part * 2];
            float2 wc = *(const float2*)&w1[(k4 * 4 + 2) * 32 + part * 2];
            float2 wd = *(const float2*)&w1[(k4 * 4 + 3) * 32 + part * 2];
            ax += h4.x * wa.x + h4.y * wb.x + h4.z * wc.x + h4.w * wd.x;
            ay += h4.x * wa.y + h4.y * wb.y + h4.z * wc.y + h4.w * wd.y;
        }
        ax = ax > 0.f ? ax : 0.f;
        ay = ay > 0.f ? ay : 0.f;
        float2 uu; uu.x = ax; uu.y = ay;
        *(float2*)&rowA[part * 2] = uu;
    }

    // ---- layer 3: 32 -> 16, relu ----
    {
        float a3 = b2[part];
#pragma unroll
        for (int k4 = 0; k4 < 8; ++k4) {
            float4 h4 = *(const float4*)&rowA[k4 * 4];
            a3 += h4.x * w2[(k4 * 4 + 0) * 16 + part]
                + h4.y * w2[(k4 * 4 + 1) * 16 + part]
                + h4.z * w2[(k4 * 4 + 2) * 16 + part]
                + h4.w * w2[(k4 * 4 + 3) * 16 + part];
        }
        a3 = a3 > 0.f ? a3 : 0.f;
        rowB[part] = a3;
    }

    // ---- layer 4: 16 -> 16, relu ----
    float r;
    {
        float a4 = b3[part];
#pragma unroll
        for (int k4 = 0; k4 < 4; ++k4) {
            float4 h4 = *(const float4*)&rowB[k4 * 4];
            a4 += h4.x * w3[(k4 * 4 + 0) * 16 + part]
                + h4.y * w3[(k4 * 4 + 1) * 16 + part]
                + h4.z * w3[(k4 * 4 + 2) * 16 + part]
                + h4.w * w3[(k4 * 4 + 3) * 16 + part];
        }
        r = a4 > 0.f ? a4 : 0.f;
    }

    if (active) rfeat[(size_t)n * 16 + part] = r;   // fully coalesced
}

// ---------------------------------------------------------------------------
// Segmented mean-pool + both heads. One block per graph (batch is sorted).
// ---------------------------------------------------------------------------
__global__ void __launch_bounds__(256)
pool_head(const float* __restrict__ rfeat, const int* __restrict__ batch,
          const float* __restrict__ w_ev, const float* __restrict__ b_ev,
          const float* __restrict__ w_env, const float* __restrict__ b_env,
          float* __restrict__ out, int n_nodes, int n_graphs)
{
    __shared__ int s_bounds[2];
    __shared__ float partial[16][17];
    __shared__ float gvec[16];

    int g = blockIdx.x;
    if (threadIdx.x < 2) {
        int target = g + threadIdx.x;          // lower_bound(batch, target)
        int lo = 0, hi = n_nodes;
        while (lo < hi) { int m = (lo + hi) >> 1; if (batch[m] < target) lo = m + 1; else hi = m; }
        s_bounds[threadIdx.x] = lo;
    }
    __syncthreads();
    int start = s_bounds[0], end = s_bounds[1];

    const int c = threadIdx.x & 15;     // channel
    const int w = threadIdx.x >> 4;     // node stream
    float acc = 0.f;
    for (int i = start + w; i < end; i += 16)
        acc += rfeat[(size_t)i * 16 + c];
    partial[w][c] = acc;
    __syncthreads();

    if (threadIdx.x < 16) {
        float s = 0.f;
#pragma unroll
        for (int ww = 0; ww < 16; ++ww) s += partial[ww][threadIdx.x];
        float cnt = (float)(end - start);
        cnt = cnt > 1.f ? cnt : 1.f;
        gvec[threadIdx.x] = s / cnt;
    }
    __syncthreads();

    if (threadIdx.x < 3) {
        int j = threadIdx.x;
        float a = b_ev[j];
#pragma unroll
        for (int k = 0; k < 16; ++k) a += gvec[k] * w_ev[k * 3 + j];
        out[(size_t)g * 3 + j] = a;
    } else if (threadIdx.x < 6) {
        int j = threadIdx.x - 3;
        float a = b_env[j];
#pragma unroll
        for (int k = 0; k < 16; ++k) a += gvec[k] * w_env[k * 3 + j];
        out[(size_t)n_graphs * 3 + (size_t)g * 3 + j] = a;
    }
}

// ---------------------------------------------------------------------------
extern "C" void kernel_launch(void* const* d_in, const int* in_sizes, int n_in,
                              void* d_out, int out_size, void* d_ws, size_t ws_size,
                              hipStream_t stream)
{
    const float* x       = (const float*)d_in[0];
    const int*   ei      = (const int*)d_in[1];
    const int*   batch   = (const int*)d_in[2];
    const float* w_gat   = (const float*)d_in[4];
    const float* att_src = (const float*)d_in[5];
    const float* att_dst = (const float*)d_in[6];
    const float* b_gat   = (const float*)d_in[7];
    const float* w_fuse  = (const float*)d_in[8];
    const float* b_fuse  = (const float*)d_in[9];
    const float* w_h1    = (const float*)d_in[10];
    const float* b_h1    = (const float*)d_in[11];
    const float* w_h2    = (const float*)d_in[12];
    const float* b_h2    = (const float*)d_in[13];
    const float* w_h3    = (const float*)d_in[14];
    const float* b_h3    = (const float*)d_in[15];
    const float* w_ev    = (const float*)d_in[16];
    const float* b_ev    = (const float*)d_in[17];
    const float* w_env   = (const float*)d_in[18];
    const float* b_env   = (const float*)d_in[19];

    const int n_nodes  = in_sizes[0] / FIN;       // 100000
    const int E        = in_sizes[1] / 2;         // 3200000
    const int n_graphs = 256;
    const int total    = E + n_nodes;             // edges incl self loops
    const int nbuck    = (n_nodes + BMASK) >> BSHIFT;   // 196

    // Workspace layout (~62 MB). bucketData overlays h0: the CSR build is
    // fully done before gat_gather writes h0.
    float* ws     = (float*)d_ws;
    __half* xh    = (__half*)ws;                          // n*64 halves
    float* h0     = ws   + (size_t)n_nodes * 32;          // n*64 fp32
    float* a_s    = h0   + (size_t)n_nodes * F;           // n*4
    float* a_d    = a_s  + (size_t)n_nodes * HEADS;       // n*4
    float* rfeat  = a_d  + (size_t)n_nodes * HEADS;       // n*16
    int*   off    = (int*)(rfeat + (size_t)n_nodes * 16); // n+1
    int*   srcs   = off    + n_nodes + 1;                 // E+n
    int*   gcount = srcs   + total;                       // nbuck
    int*   bbase  = gcount + nbuck;                       // nbuck
    int*   bucketData = (int*)h0;                         // nbuck*BCAP (14.5MB < 25.6MB)

    hipMemsetAsync(gcount, 0, (size_t)nbuck * sizeof(int), stream);

    node_prep<<<(n_nodes + 255) / 256, 256, 0, stream>>>(
        x, w_gat, att_src, att_dst, xh, a_s, a_d, n_nodes);

    // CSR build (by dst), two-level bucket sort, rebuilt every call.
    bin_pass<<<(E + 256 * BIN_EPT - 1) / (256 * BIN_EPT), 256, 0, stream>>>(
        ei, E, nbuck, gcount, bucketData);
    bucket_scan<<<1, 256, 0, stream>>>(gcount, bbase, off, nbuck, n_nodes, E);
    csr_build<<<nbuck, 256, 0, stream>>>(bucketData, gcount, bbase, off, srcs, n_nodes);

    // Gather: 8 lanes/node -> 32 nodes per 256-thread block.
    gat_gather<<<(n_nodes * 8 + 255) / 256, 256, 0, stream>>>(
        off, srcs, a_s, a_d, xh, b_gat, h0, n_nodes);

    mlp_pool2<<<(n_nodes + 15) / 16, 256, 0, stream>>>(
        h0, w_fuse, b_fuse, w_h1, b_h1, w_h2, b_h2, w_h3, b_h3,
        rfeat, n_nodes);

    pool_head<<<n_graphs, 256, 0, stream>>>(
        rfeat, batch, w_ev, b_ev, w_env, b_env, (float*)d_out, n_nodes, n_graphs);
}

// Round 9
// 332.707 us; speedup vs baseline: 12.0966x; 1.0446x over previous
//
#include <hip/hip_runtime.h>
#include <hip/hip_bf16.h>
#include <hip/hip_fp16.h>

// N=100000 nodes, F_in=20, 4 heads x 16 ch = 64, E=3.2M edges (+N self loops),
// 256 graphs. All fp32 in/out.
//
// R8: total was 348 with top dispatch (gat_gather) only 82 -> 266us of tail.
// (a) mlp_pool2 was LDS-BW bound on weight re-reads: now 2 nodes per
// 16-thread group (weights loaded to regs once, used twice) -> half the LDS
// traffic. (b) node_prep+bin_pass fused (block-range split). (c) bucket_scan
// folded into csr_build (per-block 196-int reduce). 8 -> 6 dispatches.
#define FIN 20
#define HEADS 4
#define F 64
#define NEG_SLOPE 0.2f
#define AP 68        // activation row stride (floats)
#define BSHIFT 9     // 512 nodes per bucket
#define BMASK 511
#define BCAP 18432   // per-bucket edge capacity (mean 16384, +16 sigma)
#define MAXBUCK 256
#define BIN_EPT 16   // edges per thread in bin pass

// ---------------------------------------------------------------------------
// Fused kernel 1: blocks [0, nbP) do node_prep; blocks [nbP, nbP+nbB) bin
// edges by dst bucket. The two jobs are independent.
// ---------------------------------------------------------------------------
__global__ void __launch_bounds__(256)
prep_bin(const float* __restrict__ x,
         const float* __restrict__ w_gat,
         const float* __restrict__ att_src,
         const float* __restrict__ att_dst,
         __half* __restrict__ xh,
         float* __restrict__ a_s,
         float* __restrict__ a_d,
         const int* __restrict__ ei, int E, int nbuck,
         int* __restrict__ gcount, int* __restrict__ bucketData,
         int n_nodes, int nbP)
{
    if (blockIdx.x < nbP) {
        // ---------------- node_prep ----------------
        __shared__ __align__(16) float w[FIN * F];
        __shared__ float asrc[F];
        __shared__ float adst[F];
        for (int i = threadIdx.x; i < FIN * F; i += 256) w[i] = w_gat[i];
        if (threadIdx.x < F) {
            asrc[threadIdx.x] = att_src[threadIdx.x];
            adst[threadIdx.x] = att_dst[threadIdx.x];
        }
        __syncthreads();

        int n = blockIdx.x * 256 + threadIdx.x;
        if (n >= n_nodes) return;

        float xv[FIN];
#pragma unroll
        for (int q = 0; q < FIN / 4; ++q) {
            float4 x4 = *(const float4*)&x[(size_t)n * FIN + q * 4];
            xv[q * 4 + 0] = x4.x; xv[q * 4 + 1] = x4.y;
            xv[q * 4 + 2] = x4.z; xv[q * 4 + 3] = x4.w;
        }

        float as[HEADS] = {0.f, 0.f, 0.f, 0.f};
        float ad[HEADS] = {0.f, 0.f, 0.f, 0.f};

#pragma unroll
        for (int j4 = 0; j4 < F / 4; ++j4) {
            float4 acc = make_float4(0.f, 0.f, 0.f, 0.f);
#pragma unroll
            for (int k = 0; k < FIN; ++k) {
                float4 w4 = *(const float4*)&w[k * F + j4 * 4];
                acc.x += xv[k] * w4.x;
                acc.y += xv[k] * w4.y;
                acc.z += xv[k] * w4.z;
                acc.w += xv[k] * w4.w;
            }
            __half2 p0 = __floats2half2_rn(acc.x, acc.y);
            __half2 p1 = __floats2half2_rn(acc.z, acc.w);
            float2 st;
            ((__half2*)&st)[0] = p0;
            ((__half2*)&st)[1] = p1;
            *(float2*)&xh[(size_t)n * F + j4 * 4] = st;

            int h = j4 >> 2;
            int jb = j4 * 4;
            as[h] += acc.x * asrc[jb] + acc.y * asrc[jb + 1] + acc.z * asrc[jb + 2] + acc.w * asrc[jb + 3];
            ad[h] += acc.x * adst[jb] + acc.y * adst[jb + 1] + acc.z * adst[jb + 2] + acc.w * adst[jb + 3];
        }
#pragma unroll
        for (int h = 0; h < HEADS; ++h) {
            a_s[(size_t)n * HEADS + h] = as[h];
            a_d[(size_t)n * HEADS + h] = ad[h];
        }
    } else {
        // ---------------- bin_pass ----------------
        __shared__ int lcnt[MAXBUCK];
        __shared__ int lbase[MAXBUCK];
        for (int i = threadIdx.x; i < nbuck; i += 256) lcnt[i] = 0;
        __syncthreads();

        int base = (blockIdx.x - nbP) * (256 * BIN_EPT);
        int b_[BIN_EPT], w_[BIN_EPT];
#pragma unroll
        for (int j = 0; j < BIN_EPT; ++j) {
            int e = base + j * 256 + threadIdx.x;
            if (e < E) {
                int src = ei[e];
                int dst = ei[E + e];
                b_[j] = dst >> BSHIFT;
                w_[j] = ((dst & BMASK) << 17) | src;   // src < 2^17 (N=100000)
                atomicAdd(&lcnt[b_[j]], 1);
            } else b_[j] = -1;
        }
        __syncthreads();
        for (int i = threadIdx.x; i < nbuck; i += 256) {
            int c = lcnt[i];
            lbase[i] = c ? atomicAdd(&gcount[i], c) : 0;
            lcnt[i] = 0;
        }
        __syncthreads();
#pragma unroll
        for (int j = 0; j < BIN_EPT; ++j) {
            if (b_[j] >= 0) {
                int p = lbase[b_[j]] + atomicAdd(&lcnt[b_[j]], 1);
                if (p < BCAP) bucketData[(size_t)b_[j] * BCAP + p] = w_[j];
            }
        }
    }
}

// ---------------------------------------------------------------------------
// CSR build: one block per bucket. Computes its own base (reduce over
// gcount[0..b) + b*512 self-loop offset), LDS histogram + scan of the
// bucket's <=512 nodes, writes off[] coalesced, plants self loops, scatters
// real edges within the bucket's ~70KB L2-resident window.
// ---------------------------------------------------------------------------
__global__ void __launch_bounds__(256)
csr_build(const int* __restrict__ bucketData, const int* __restrict__ gcount,
          int* __restrict__ off, int* __restrict__ srcs,
          int n_nodes, int total_edges)
{
    __shared__ int hist[512];     // reused as per-node cursor after the scan
    __shared__ int psum[256];
    int b = blockIdx.x;
    int t = threadIdx.x;
    int cnt = gcount[b]; if (cnt > BCAP) cnt = BCAP;
    int node0 = b << BSHIFT;
    int nnode = n_nodes - node0; if (nnode > 512) nnode = 512;

    // ---- per-block prefix of gcount (replaces the bucket_scan kernel) ----
    psum[t] = (t < b) ? gcount[t] : 0;       // nbuck <= 256
    __syncthreads();
    for (int d = 128; d > 0; d >>= 1) {
        if (t < d) psum[t] += psum[t + d];
        __syncthreads();
    }
    int base = psum[0] + node0;              // + node0: self loops of earlier buckets
    __syncthreads();                         // psum free for reuse
    if (b == 0 && t == 0) off[n_nodes] = total_edges;

    hist[t] = 0; hist[t + 256] = 0;
    __syncthreads();
    const int* bd = bucketData + (size_t)b * BCAP;
    for (int i = t; i < cnt; i += 256) atomicAdd(&hist[bd[i] >> 17], 1);
    __syncthreads();

    int i0 = 2 * t, i1 = 2 * t + 1;
    int v0 = (i0 < nnode) ? hist[i0] + 1 : 0;   // +1: self loop slot
    int v1 = (i1 < nnode) ? hist[i1] + 1 : 0;
    psum[t] = v0 + v1;
    __syncthreads();
    for (int d = 1; d < 256; d <<= 1) {
        int w = (t >= d) ? psum[t - d] : 0;
        __syncthreads();
        psum[t] += w;
        __syncthreads();
    }
    int ex = (t == 0) ? 0 : psum[t - 1];
    __syncthreads();                 // hist reads done; reuse as cursor
    if (i0 < nnode) {
        int o = base + ex;
        off[node0 + i0] = o;
        srcs[o] = node0 + i0;        // self loop first
        hist[i0] = o + 1;
    }
    if (i1 < nnode) {
        int o = base + ex + v0;
        off[node0 + i1] = o;
        srcs[o] = node0 + i1;
        hist[i1] = o + 1;
    }
    __syncthreads();
    for (int i = t; i < cnt; i += 256) {
        int w = bd[i];
        int p = atomicAdd(&hist[w >> 17], 1);
        srcs[p] = w & 0x1FFFF;
    }
}

// ---------------------------------------------------------------------------
// Gather: 8 lanes per node, branch-free clamped 8-edge chunks, no LDS.
// Writes h0 = acc/z + b_gat.
// ---------------------------------------------------------------------------
__global__ void __launch_bounds__(256)
gat_gather(const int* __restrict__ off,
           const int* __restrict__ srcs,
           const float* __restrict__ a_s,
           const float* __restrict__ a_d,
           const __half* __restrict__ xh,
           const float* __restrict__ b_gat,
           float* __restrict__ h0out,
           int n_nodes)
{
    int tid = blockIdx.x * 256 + threadIdx.x;
    int n = tid >> 3;
    int part = tid & 7;
    if (n >= n_nodes) return;
    const int h = part >> 1;
    const int g8 = (threadIdx.x & 63) >> 3;   // node slot within wave (0..7)

    int kb = off[n];
    int ke = off[n + 1];
    float adh = a_d[n * 4 + h];

    float acc[8] = {0.f, 0.f, 0.f, 0.f, 0.f, 0.f, 0.f, 0.f};
    float zacc = 0.f;

    for (int base = kb; base < ke; base += 8) {
        int idx = base + part;
        idx = idx < ke - 1 ? idx : ke - 1;       // clamp: always valid load
        int my_s = srcs[idx];
#pragma unroll
        for (int j = 0; j < 8; ++j) {
            int s = __shfl(my_s, g8 * 8 + j, 64);
            float l = a_s[s * 4 + h] + adh;
            l = l > 0.f ? l : NEG_SLOPE * l;
            float e = (base + j < ke) ? __expf(l) : 0.f;
            zacc += e;
            float4 raw = *(const float4*)&xh[(size_t)s * F + part * 8];  // 8 halves
            const __half2* hp = (const __half2*)&raw;
            float2 c0 = __half22float2(hp[0]);
            float2 c1 = __half22float2(hp[1]);
            float2 c2 = __half22float2(hp[2]);
            float2 c3 = __half22float2(hp[3]);
            acc[0] += e * c0.x; acc[1] += e * c0.y;
            acc[2] += e * c1.x; acc[3] += e * c1.y;
            acc[4] += e * c2.x; acc[5] += e * c2.y;
            acc[6] += e * c3.x; acc[7] += e * c3.y;
        }
    }

    float inv = 1.f / zacc;            // zacc > 0 always (self loop)
    float4 bg0 = *(const float4*)&b_gat[part * 8];
    float4 bg1 = *(const float4*)&b_gat[part * 8 + 4];
    float4 o0, o1;
    o0.x = acc[0] * inv + bg0.x; o0.y = acc[1] * inv + bg0.y;
    o0.z = acc[2] * inv + bg0.z; o0.w = acc[3] * inv + bg0.w;
    o1.x = acc[4] * inv + bg1.x; o1.y = acc[5] * inv + bg1.y;
    o1.z = acc[6] * inv + bg1.z; o1.w = acc[7] * inv + bg1.w;
    *(float4*)&h0out[(size_t)n * F + part * 8]     = o0;
    *(float4*)&h0out[(size_t)n * F + part * 8 + 4] = o1;
}

// ---------------------------------------------------------------------------
// MLP. 16 threads per node-PAIR (nodes n and n+16 of a 32-node block): each
// weight register load feeds both nodes' FMAs -> half the LDS weight traffic
// per node. Activations ping-pong through LDS (wave-synchronous).
// ---------------------------------------------------------------------------
__global__ void __launch_bounds__(256)
mlp_pool2(const float* __restrict__ h0g,
          const float* __restrict__ w_fuse, const float* __restrict__ b_fuse,
          const float* __restrict__ w_h1, const float* __restrict__ b_h1,
          const float* __restrict__ w_h2, const float* __restrict__ b_h2,
          const float* __restrict__ w_h3, const float* __restrict__ b_h3,
          float* __restrict__ rfeat,
          int n_nodes)
{
    __shared__ __align__(16) float wf[64 * 64];
    __shared__ __align__(16) float w1[64 * 32];
    __shared__ __align__(16) float w2[32 * 16];
    __shared__ __align__(16) float w3[16 * 16];
    __shared__ __align__(16) float bf[64];
    __shared__ __align__(16) float b1[32], b2[16], b3[16];
    __shared__ __align__(16) float actA[32 * AP];
    __shared__ __align__(16) float actB[32 * AP];

    for (int i = threadIdx.x; i < 64 * 64; i += 256) wf[i] = w_fuse[i];
    for (int i = threadIdx.x; i < 64 * 32; i += 256) w1[i] = w_h1[i];
    for (int i = threadIdx.x; i < 32 * 16; i += 256) w2[i] = w_h2[i];
    for (int i = threadIdx.x; i < 16 * 16; i += 256) w3[i] = w_h3[i];
    if (threadIdx.x < 64) bf[threadIdx.x] = b_fuse[threadIdx.x];
    else if (threadIdx.x < 96)  b1[threadIdx.x - 64] = b_h1[threadIdx.x - 64];
    else if (threadIdx.x < 112) b2[threadIdx.x - 96] = b_h2[threadIdx.x - 96];
    else if (threadIdx.x < 128) b3[threadIdx.x - 112] = b_h3[threadIdx.x - 112];

    const int node_l = threadIdx.x >> 4;        // 0..15: slot = node pair
    const int part   = threadIdx.x & 15;
    const int nA     = blockIdx.x * 32 + node_l;
    const int nB     = nA + 16;
    const bool actvA = (nA < n_nodes);
    const bool actvB = (nB < n_nodes);

    float4 h0A = make_float4(0.f, 0.f, 0.f, 0.f);
    float4 h0B = make_float4(0.f, 0.f, 0.f, 0.f);
    if (actvA) h0A = *(const float4*)&h0g[(size_t)nA * F + part * 4];
    if (actvB) h0B = *(const float4*)&h0g[(size_t)nB * F + part * 4];
    __syncthreads();

    float* rowAa = &actA[node_l * AP];
    float* rowAb = &actA[(node_l + 16) * AP];
    float* rowBa = &actB[node_l * AP];
    float* rowBb = &actB[(node_l + 16) * AP];
    *(float4*)&rowAa[part * 4] = h0A;
    *(float4*)&rowAb[part * 4] = h0B;

    // ---- layer 1: 64 -> 64, relu ----
    {
        float4 aA = *(const float4*)&bf[part * 4];
        float4 aB = aA;
#pragma unroll
        for (int k4 = 0; k4 < 16; ++k4) {
            float4 hA = *(const float4*)&rowAa[k4 * 4];
            float4 hB = *(const float4*)&rowAb[k4 * 4];
            float4 w0 = *(const float4*)&wf[(k4 * 4 + 0) * 64 + part * 4];
            float4 wq1 = *(const float4*)&wf[(k4 * 4 + 1) * 64 + part * 4];
            float4 wq2 = *(const float4*)&wf[(k4 * 4 + 2) * 64 + part * 4];
            float4 wq3 = *(const float4*)&wf[(k4 * 4 + 3) * 64 + part * 4];
            aA.x += hA.x * w0.x + hA.y * wq1.x + hA.z * wq2.x + hA.w * wq3.x;
            aA.y += hA.x * w0.y + hA.y * wq1.y + hA.z * wq2.y + hA.w * wq3.y;
            aA.z += hA.x * w0.z + hA.y * wq1.z + hA.z * wq2.z + hA.w * wq3.z;
            aA.w += hA.x * w0.w + hA.y * wq1.w + hA.z * wq2.w + hA.w * wq3.w;
            aB.x += hB.x * w0.x + hB.y * wq1.x + hB.z * wq2.x + hB.w * wq3.x;
            aB.y += hB.x * w0.y + hB.y * wq1.y + hB.z * wq2.y + hB.w * wq3.y;
            aB.z += hB.x * w0.z + hB.y * wq1.z + hB.z * wq2.z + hB.w * wq3.z;
            aB.w += hB.x * w0.w + hB.y * wq1.w + hB.z * wq2.w + hB.w * wq3.w;
        }
        aA.x = aA.x > 0.f ? aA.x : 0.f; aA.y = aA.y > 0.f ? aA.y : 0.f;
        aA.z = aA.z > 0.f ? aA.z : 0.f; aA.w = aA.w > 0.f ? aA.w : 0.f;
        aB.x = aB.x > 0.f ? aB.x : 0.f; aB.y = aB.y > 0.f ? aB.y : 0.f;
        aB.z = aB.z > 0.f ? aB.z : 0.f; aB.w = aB.w > 0.f ? aB.w : 0.f;
        *(float4*)&rowBa[part * 4] = aA;
        *(float4*)&rowBb[part * 4] = aB;
    }

    // ---- layer 2: 64 -> 32, relu ----
    {
        float axA = b1[part * 2], ayA = b1[part * 2 + 1];
        float axB = axA, ayB = ayA;
#pragma unroll
        for (int k4 = 0; k4 < 16; ++k4) {
            float4 hA = *(const float4*)&rowBa[k4 * 4];
            float4 hB = *(const float4*)&rowBb[k4 * 4];
            float2 wa = *(const float2*)&w1[(k4 * 4 + 0) * 32 + part * 2];
            float2 wb = *(const float2*)&w1[(k4 * 4 + 1) * 32 + part * 2];
            float2 wc = *(const float2*)&w1[(k4 * 4 + 2) * 32 + part * 2];
            float2 wd = *(const float2*)&w1[(k4 * 4 + 3) * 32 + part * 2];
            axA += hA.x * wa.x + hA.y * wb.x + hA.z * wc.x + hA.w * wd.x;
            ayA += hA.x * wa.y + hA.y * wb.y + hA.z * wc.y + hA.w * wd.y;
            axB += hB.x * wa.x + hB.y * wb.x + hB.z * wc.x + hB.w * wd.x;
            ayB += hB.x * wa.y + hB.y * wb.y + hB.z * wc.y + hB.w * wd.y;
        }
        axA = axA > 0.f ? axA : 0.f; ayA = ayA > 0.f ? ayA : 0.f;
        axB = axB > 0.f ? axB : 0.f; ayB = ayB > 0.f ? ayB : 0.f;
        float2 uA; uA.x = axA; uA.y = ayA;
        float2 uB; uB.x = axB; uB.y = ayB;
        *(float2*)&rowAa[part * 2] = uA;
        *(float2*)&rowAb[part * 2] = uB;
    }

    // ---- layer 3: 32 -> 16, relu ----
    {
        float aA = b2[part], aB = aA;
#pragma unroll
        for (int k4 = 0; k4 < 8; ++k4) {
            float4 hA = *(const float4*)&rowAa[k4 * 4];
            float4 hB = *(const float4*)&rowAb[k4 * 4];
            float w0 = w2[(k4 * 4 + 0) * 16 + part];
            float wq1 = w2[(k4 * 4 + 1) * 16 + part];
            float wq2 = w2[(k4 * 4 + 2) * 16 + part];
            float wq3 = w2[(k4 * 4 + 3) * 16 + part];
            aA += hA.x * w0 + hA.y * wq1 + hA.z * wq2 + hA.w * wq3;
            aB += hB.x * w0 + hB.y * wq1 + hB.z * wq2 + hB.w * wq3;
        }
        aA = aA > 0.f ? aA : 0.f;
        aB = aB > 0.f ? aB : 0.f;
        rowBa[part] = aA;
        rowBb[part] = aB;
    }

    // ---- layer 4: 16 -> 16, relu ----
    float rA, rB;
    {
        float aA = b3[part], aB = aA;
#pragma unroll
        for (int k4 = 0; k4 < 4; ++k4) {
            float4 hA = *(const float4*)&rowBa[k4 * 4];
            float4 hB = *(const float4*)&rowBb[k4 * 4];
            float w0 = w3[(k4 * 4 + 0) * 16 + part];
            float wq1 = w3[(k4 * 4 + 1) * 16 + part];
            float wq2 = w3[(k4 * 4 + 2) * 16 + part];
            float wq3 = w3[(k4 * 4 + 3) * 16 + part];
            aA += hA.x * w0 + hA.y * wq1 + hA.z * wq2 + hA.w * wq3;
            aB += hB.x * w0 + hB.y * wq1 + hB.z * wq2 + hB.w * wq3;
        }
        rA = aA > 0.f ? aA : 0.f;
        rB = aB > 0.f ? aB : 0.f;
    }

    if (actvA) rfeat[(size_t)nA * 16 + part] = rA;   // fully coalesced
    if (actvB) rfeat[(size_t)nB * 16 + part] = rB;
}

// ---------------------------------------------------------------------------
// Segmented mean-pool + both heads. One block per graph (batch is sorted).
// ---------------------------------------------------------------------------
__global__ void __launch_bounds__(256)
pool_head(const float* __restrict__ rfeat, const int* __restrict__ batch,
          const float* __restrict__ w_ev, const float* __restrict__ b_ev,
          const float* __restrict__ w_env, const float* __restrict__ b_env,
          float* __restrict__ out, int n_nodes, int n_graphs)
{
    __shared__ int s_bounds[2];
    __shared__ float partial[16][17];
    __shared__ float gvec[16];

    int g = blockIdx.x;
    if (threadIdx.x < 2) {
        int target = g + threadIdx.x;          // lower_bound(batch, target)
        int lo = 0, hi = n_nodes;
        while (lo < hi) { int m = (lo + hi) >> 1; if (batch[m] < target) lo = m + 1; else hi = m; }
        s_bounds[threadIdx.x] = lo;
    }
    __syncthreads();
    int start = s_bounds[0], end = s_bounds[1];

    const int c = threadIdx.x & 15;     // channel
    const int w = threadIdx.x >> 4;     // node stream
    float acc = 0.f;
    for (int i = start + w; i < end; i += 16)
        acc += rfeat[(size_t)i * 16 + c];
    partial[w][c] = acc;
    __syncthreads();

    if (threadIdx.x < 16) {
        float s = 0.f;
#pragma unroll
        for (int ww = 0; ww < 16; ++ww) s += partial[ww][threadIdx.x];
        float cnt = (float)(end - start);
        cnt = cnt > 1.f ? cnt : 1.f;
        gvec[threadIdx.x] = s / cnt;
    }
    __syncthreads();

    if (threadIdx.x < 3) {
        int j = threadIdx.x;
        float a = b_ev[j];
#pragma unroll
        for (int k = 0; k < 16; ++k) a += gvec[k] * w_ev[k * 3 + j];
        out[(size_t)g * 3 + j] = a;
    } else if (threadIdx.x < 6) {
        int j = threadIdx.x - 3;
        float a = b_env[j];
#pragma unroll
        for (int k = 0; k < 16; ++k) a += gvec[k] * w_env[k * 3 + j];
        out[(size_t)n_graphs * 3 + (size_t)g * 3 + j] = a;
    }
}

// ---------------------------------------------------------------------------
extern "C" void kernel_launch(void* const* d_in, const int* in_sizes, int n_in,
                              void* d_out, int out_size, void* d_ws, size_t ws_size,
                              hipStream_t stream)
{
    const float* x       = (const float*)d_in[0];
    const int*   ei      = (const int*)d_in[1];
    const int*   batch   = (const int*)d_in[2];
    const float* w_gat   = (const float*)d_in[4];
    const float* att_src = (const float*)d_in[5];
    const float* att_dst = (const float*)d_in[6];
    const float* b_gat   = (const float*)d_in[7];
    const float* w_fuse  = (const float*)d_in[8];
    const float* b_fuse  = (const float*)d_in[9];
    const float* w_h1    = (const float*)d_in[10];
    const float* b_h1    = (const float*)d_in[11];
    const float* w_h2    = (const float*)d_in[12];
    const float* b_h2    = (const float*)d_in[13];
    const float* w_h3    = (const float*)d_in[14];
    const float* b_h3    = (const float*)d_in[15];
    const float* w_ev    = (const float*)d_in[16];
    const float* b_ev    = (const float*)d_in[17];
    const float* w_env   = (const float*)d_in[18];
    const float* b_env   = (const float*)d_in[19];

    const int n_nodes  = in_sizes[0] / FIN;       // 100000
    const int E        = in_sizes[1] / 2;         // 3200000
    const int n_graphs = 256;
    const int total    = E + n_nodes;             // edges incl self loops
    const int nbuck    = (n_nodes + BMASK) >> BSHIFT;   // 196

    // Workspace layout (~62 MB). bucketData overlays h0: the CSR build is
    // fully done before gat_gather writes h0.
    float* ws     = (float*)d_ws;
    __half* xh    = (__half*)ws;                          // n*64 halves
    float* h0     = ws   + (size_t)n_nodes * 32;          // n*64 fp32
    float* a_s    = h0   + (size_t)n_nodes * F;           // n*4
    float* a_d    = a_s  + (size_t)n_nodes * HEADS;       // n*4
    float* rfeat  = a_d  + (size_t)n_nodes * HEADS;       // n*16
    int*   off    = (int*)(rfeat + (size_t)n_nodes * 16); // n+1
    int*   srcs   = off    + n_nodes + 1;                 // E+n
    int*   gcount = srcs   + total;                       // nbuck
    int*   bucketData = (int*)h0;                         // nbuck*BCAP (14.5MB < 25.6MB)

    hipMemsetAsync(gcount, 0, (size_t)nbuck * sizeof(int), stream);

    const int nbP = (n_nodes + 255) / 256;                     // 391
    const int nbB = (E + 256 * BIN_EPT - 1) / (256 * BIN_EPT); // 782

    prep_bin<<<nbP + nbB, 256, 0, stream>>>(
        x, w_gat, att_src, att_dst, xh, a_s, a_d,
        ei, E, nbuck, gcount, bucketData, n_nodes, nbP);

    csr_build<<<nbuck, 256, 0, stream>>>(
        bucketData, gcount, off, srcs, n_nodes, total);

    // Gather: 8 lanes/node -> 32 nodes per 256-thread block.
    gat_gather<<<(n_nodes * 8 + 255) / 256, 256, 0, stream>>>(
        off, srcs, a_s, a_d, xh, b_gat, h0, n_nodes);

    mlp_pool2<<<(n_nodes + 31) / 32, 256, 0, stream>>>(
        h0, w_fuse, b_fuse, w_h1, b_h1, w_h2, b_h2, w_h3, b_h3,
        rfeat, n_nodes);

    pool_head<<<n_graphs, 256, 0, stream>>>(
        rfeat, batch, w_ev, b_ev, w_env, b_env, (float*)d_out, n_nodes, n_graphs);
}